// Round 3
// baseline (7128.355 us; speedup 1.0000x reference)
//
#include <hip/hip_runtime.h>
#include <hip/hip_bf16.h>
#include <cstdint>
#include <cstddef>

// Problem constants: B=32, G=512, S=128, GS=32, P=10, C=384, H=6, D=64,
// HID=1536, RED=16, tokens per batch = 513.
typedef __hip_bfloat16 bf16;
constexpr int TOK = 32 * 513;   // 16416 rows in the residual stream

__device__ __forceinline__ float bflo(unsigned u){ return __uint_as_float(u << 16); }
__device__ __forceinline__ float bfhi(unsigned u){ return __uint_as_float(u & 0xffff0000u); }
__device__ __forceinline__ float b2f(bf16 x){ return __bfloat162float(x); }
__device__ __forceinline__ bf16  f2b(float x){ return __float2bfloat16(x); }
__device__ __forceinline__ float geluf(float x){ return 0.5f*x*(1.0f + erff(x*0.70710678118654752f)); }
__device__ __forceinline__ void unp8(uint4 u, float* f){
  f[0]=bflo(u.x); f[1]=bfhi(u.x); f[2]=bflo(u.y); f[3]=bfhi(u.y);
  f[4]=bflo(u.z); f[5]=bfhi(u.z); f[6]=bflo(u.w); f[7]=bfhi(u.w);
}
// Scalar decode robust to int32-vs-float32 materialization of Python scalars.
__device__ __forceinline__ float scal(const int* p){
  const int i = *p;
  if (i > -1000000 && i < 1000000) return (float)i;
  return __int_as_float(i);
}

// ---------------------------------------------------------------------------
// Dtype detection: if any 16-bit half of x's first 2048 words, viewed as bf16,
// is NaN or |v|>1e6 => inputs are fp32 (flag=1). bf16 inputs (|x|<~6) => 0.
// ---------------------------------------------------------------------------
__global__ __launch_bounds__(256) void detect_kernel(const unsigned* __restrict__ x,
                                                     int* __restrict__ flag)
{
  const int t = threadIdx.x;
  bool bad = false;
  for (int i = t; i < 2048; i += 256){
    const unsigned u = x[i];
    const float a = fabsf(bflo(u)), b = fabsf(bfhi(u));
    if (!(a < 1e6f) || !(b < 1e6f)) bad = true;   // NaN fails the compare
  }
  __shared__ int s;
  if (t == 0) s = 0;
  __syncthreads();
  const unsigned long long m = __ballot(bad);
  if (m != 0ull && (t & 63) == 0) atomicOr(&s, 1);
  __syncthreads();
  if (t == 0) *flag = s;
}

// ---------------------------------------------------------------------------
// Canonicalize all float inputs to bf16 (copy if already bf16).
// grid.y selects the input; grid.x*256 threads stride over it.
// ---------------------------------------------------------------------------
struct ConvArgs {
  const void* src[34];
  bf16*       dst[34];
  int         n[34];
};
__global__ __launch_bounds__(256) void convert_many(const int* __restrict__ flag, ConvArgs a)
{
  const int ii = blockIdx.y;
  const bool isf = (*flag != 0);
  const int n = a.n[ii];
  const void* s = a.src[ii];
  bf16* d = a.dst[ii];
  for (int i = blockIdx.x*256 + threadIdx.x; i < n; i += gridDim.x*256){
    d[i] = isf ? f2b(((const float*)s)[i]) : ((const bf16*)s)[i];
  }
}

// ---------------------------------------------------------------------------
// LayerNorm: one wave per row of 384. Output bf16.
// ---------------------------------------------------------------------------
template<bool SRC_BF16>
__global__ __launch_bounds__(256) void ln_kernel(const void* __restrict__ src,
    const bf16* __restrict__ g, const bf16* __restrict__ b,
    bf16* __restrict__ out, int rows)
{
  const int wave = (blockIdx.x * blockDim.x + threadIdx.x) >> 6;
  const int lane = threadIdx.x & 63;
  if (wave >= rows) return;
  float v[6]; float s = 0.f, s2 = 0.f;
  #pragma unroll
  for (int i = 0; i < 6; i++){
    const int c = lane + 64*i;
    float x;
    if (SRC_BF16) x = b2f(((const bf16*)src)[(size_t)wave*384 + c]);
    else          x = ((const float*)src)[(size_t)wave*384 + c];
    v[i] = x; s += x; s2 += x*x;
  }
  #pragma unroll
  for (int mm = 32; mm; mm >>= 1){ s += __shfl_xor(s, mm); s2 += __shfl_xor(s2, mm); }
  const float mean = s * (1.f/384.f);
  const float rs = rsqrtf(s2 * (1.f/384.f) - mean*mean + 1e-5f);
  #pragma unroll
  for (int i = 0; i < 6; i++){
    const int c = lane + 64*i;
    out[(size_t)wave*384 + c] = f2b((v[i]-mean)*rs*b2f(g[c]) + b2f(b[c]));
  }
}

// ---------------------------------------------------------------------------
// Tiled GEMM: out[M,N] = A[M,K] @ W[K,N] (+bias, epilogue). fp32 accumulate.
// Block tile 128x64, BK=16, 256 threads, 8x4 microtile. A is bf16.
// EPI: 0 = bf16 out, +bias            (mlp2 -> h)
//      1 = bf16 out, no bias          (qkv)
//      2 = bf16 out, gelu(+bias)      (mlp1 -> h1)
//      3 = f32 out, +bias +bf16resid  (attn proj -> xres)
// ---------------------------------------------------------------------------
template<int EPI>
__global__ __launch_bounds__(256) void gemm_kernel(
    const bf16* __restrict__ A, const bf16* __restrict__ W,
    const bf16* __restrict__ bias, const bf16* __restrict__ resid,
    void* __restrict__ outv, int M, int N, int K)
{
  __shared__ float As[16][129];   // [k][m], +1 pad
  __shared__ float Ws[16][64];    // [k][n]
  const int t  = threadIdx.x;
  const int m0 = blockIdx.y * 128;
  const int n0 = blockIdx.x * 64;
  const int tx = t & 15, ty = t >> 4;
  float acc[8][4];
  #pragma unroll
  for (int i = 0; i < 8; i++){
    #pragma unroll
    for (int j = 0; j < 4; j++) acc[i][j] = 0.f;
  }
  const int ar  = t >> 1;          // A row within tile (0..127)
  const int kc  = (t & 1) * 8;     // A k offset (0/8)
  const int wkr = t >> 4;          // W k row (0..15)
  const int wnc = (t & 15) * 4;    // W n offset

  for (int k0 = 0; k0 < K; k0 += 16){
    float av[8];
    const int gm = m0 + ar;
    if (gm < M){
      uint4 u = *(const uint4*)(A + (size_t)gm*K + k0 + kc);
      unp8(u, av);
    } else {
      #pragma unroll
      for (int i = 0; i < 8; i++) av[i] = 0.f;
    }
    #pragma unroll
    for (int i = 0; i < 8; i++) As[kc+i][ar] = av[i];
    {
      uint2 u = *(const uint2*)(W + (size_t)(k0+wkr)*N + n0 + wnc);
      Ws[wkr][wnc+0]=bflo(u.x); Ws[wkr][wnc+1]=bfhi(u.x);
      Ws[wkr][wnc+2]=bflo(u.y); Ws[wkr][wnc+3]=bfhi(u.y);
    }
    __syncthreads();
    #pragma unroll
    for (int kk = 0; kk < 16; kk++){
      float a[8];
      #pragma unroll
      for (int i = 0; i < 8; i++) a[i] = As[kk][ty*8+i];
      float4 wb = *(const float4*)&Ws[kk][tx*4];
      #pragma unroll
      for (int i = 0; i < 8; i++){
        acc[i][0] = fmaf(a[i], wb.x, acc[i][0]);
        acc[i][1] = fmaf(a[i], wb.y, acc[i][1]);
        acc[i][2] = fmaf(a[i], wb.z, acc[i][2]);
        acc[i][3] = fmaf(a[i], wb.w, acc[i][3]);
      }
    }
    __syncthreads();
  }
  const int gn0 = n0 + tx*4;
  #pragma unroll
  for (int i = 0; i < 8; i++){
    const int gm = m0 + ty*8 + i;
    if (gm < M){
      #pragma unroll
      for (int j = 0; j < 4; j++){
        float v = acc[i][j];
        const int gn = gn0 + j;
        const size_t o = (size_t)gm*N + gn;
        if (EPI == 0){ v += b2f(bias[gn]); ((bf16*)outv)[o] = f2b(v); }
        else if (EPI == 1){ ((bf16*)outv)[o] = f2b(v); }
        else if (EPI == 2){ v += b2f(bias[gn]); ((bf16*)outv)[o] = f2b(geluf(v)); }
        else { v += b2f(bias[gn]) + b2f(resid[o]); ((float*)outv)[o] = v; }
      }
    }
  }
}

// ---------------------------------------------------------------------------
// Prompt QKV: (10 x 384) @ (384 x 1152) -> f32 (prompt used WITHOUT LN).
// ---------------------------------------------------------------------------
__global__ __launch_bounds__(256) void pqkv_kernel(const bf16* __restrict__ pe,
    const bf16* __restrict__ Wqkv, float* __restrict__ pq)
{
  const int n  = blockIdx.x*64 + (threadIdx.x & 63);
  const int rg = threadIdx.x >> 6;
  for (int r = rg; r < 10; r += 4){
    float s0 = 0.f, s1 = 0.f;
    for (int c = 0; c < 384; c += 2){
      s0 = fmaf(b2f(pe[(size_t)r*384+c]),   b2f(Wqkv[(size_t)c*1152 + n]),     s0);
      s1 = fmaf(b2f(pe[(size_t)r*384+c+1]), b2f(Wqkv[(size_t)(c+1)*1152 + n]), s1);
    }
    pq[(size_t)r*1152 + n] = s0 + s1;
  }
}

// ---------------------------------------------------------------------------
// Main attention (513 keys, flash-style) + prompt cross-attention fused.
// grid = (17 q-chunks of 32 rows, 192 b*h). 256 threads = 4 waves x 8 rows.
// ---------------------------------------------------------------------------
__global__ __launch_bounds__(256) void attn_kernel(
    const bf16* __restrict__ qkv, const float* __restrict__ pq,
    const bf16* __restrict__ gate, bf16* __restrict__ ao)
{
  __shared__ float KtT[64][65];   // [d][j] transposed
  __shared__ float Vt[64][65];    // [j][d]
  __shared__ float Qr[32][64];
  __shared__ float Pk[10][65];
  __shared__ float Pv[10][65];
  const int bh = blockIdx.y;
  const int b = bh / 6, h = bh % 6;
  const int r0 = blockIdx.x * 32;
  const int t = threadIdx.x;
  const int lane = t & 63;
  const int w = t >> 6;

  { // stage q rows
    const int rr = t >> 3, dc = (t & 7) * 8;
    const int tok = r0 + rr;
    float f[8];
    if (tok < 513){
      uint4 u = *(const uint4*)(qkv + (size_t)(b*513 + tok)*1152 + h*64 + dc);
      unp8(u, f);
    } else {
      #pragma unroll
      for (int i = 0; i < 8; i++) f[i] = 0.f;
    }
    #pragma unroll
    for (int i = 0; i < 8; i++) Qr[rr][dc+i] = f[i];
  }
  if (t < 160){ // prompt k/v for this head
    const int j = t >> 4, dc = (t & 15) * 4;
    const float* pk = pq + (size_t)j*1152 + 384 + h*64 + dc;
    const float* pv = pq + (size_t)j*1152 + 768 + h*64 + dc;
    #pragma unroll
    for (int i = 0; i < 4; i++){ Pk[j][dc+i] = pk[i]; Pv[j][dc+i] = pv[i]; }
  }
  __syncthreads();

  float m_i[8], l_i[8], acc[8];
  #pragma unroll
  for (int i = 0; i < 8; i++){ m_i[i] = -30000.f; l_i[i] = 0.f; acc[i] = 0.f; }

  for (int kt = 0; kt < 9; kt++){
    const int kb = kt * 64;
    { // stage K (transposed) and V tiles
      const int j = t >> 2, dc = (t & 3) * 16;
      const int tok = kb + j;
      float fk[16], fv[16];
      if (tok < 513){
        const bf16* base = qkv + (size_t)(b*513 + tok)*1152 + h*64 + dc;
        unp8(*(const uint4*)(base + 384), fk);
        unp8(*(const uint4*)(base + 392), fk + 8);
        unp8(*(const uint4*)(base + 768), fv);
        unp8(*(const uint4*)(base + 776), fv + 8);
      } else {
        #pragma unroll
        for (int i = 0; i < 16; i++){ fk[i] = 0.f; fv[i] = 0.f; }
      }
      #pragma unroll
      for (int i = 0; i < 16; i++){ KtT[dc+i][j] = fk[i]; Vt[j][dc+i] = fv[i]; }
    }
    __syncthreads();
    const int nv = (513 - kb < 64) ? (513 - kb) : 64;
    for (int i = 0; i < 8; i++){
      const int r = w*8 + i;
      if (r0 + r < 513){   // wave-uniform
        float s = -30000.f;
        if (lane < nv){
          float s0=0.f, s1=0.f, s2=0.f, s3=0.f;
          #pragma unroll 4
          for (int d = 0; d < 64; d += 4){
            s0 = fmaf(Qr[r][d+0], KtT[d+0][lane], s0);
            s1 = fmaf(Qr[r][d+1], KtT[d+1][lane], s1);
            s2 = fmaf(Qr[r][d+2], KtT[d+2][lane], s2);
            s3 = fmaf(Qr[r][d+3], KtT[d+3][lane], s3);
          }
          s = ((s0+s1)+(s2+s3)) * 0.125f;
        }
        float mt = s;
        #pragma unroll
        for (int mm = 32; mm; mm >>= 1) mt = fmaxf(mt, __shfl_xor(mt, mm));
        const float mn = fmaxf(m_i[i], mt);
        const float al = __expf(m_i[i] - mn);
        float p = (lane < nv) ? __expf(s - mn) : 0.f;
        float ps = p;
        #pragma unroll
        for (int mm = 32; mm; mm >>= 1) ps += __shfl_xor(ps, mm);
        l_i[i] = l_i[i]*al + ps;
        m_i[i] = mn;
        float a0 = acc[i]*al, a1 = 0.f;
        #pragma unroll 8
        for (int j2 = 0; j2 < 64; j2 += 2){
          a0 = fmaf(__shfl(p, j2),   Vt[j2][lane],   a0);
          a1 = fmaf(__shfl(p, j2+1), Vt[j2+1][lane], a1);
        }
        acc[i] = a0 + a1;
      }
    }
    __syncthreads();
  }

  const float gh = b2f(gate[h]);
  for (int i = 0; i < 8; i++){
    const int r = w*8 + i;
    const int tok = r0 + r;
    if (tok < 513){
      float s = -30000.f;
      if (lane < 10){
        float s0=0.f, s1=0.f;
        #pragma unroll 8
        for (int d = 0; d < 64; d += 2){
          s0 = fmaf(Qr[r][d],   Pk[lane][d],   s0);
          s1 = fmaf(Qr[r][d+1], Pk[lane][d+1], s1);
        }
        s = (s0+s1) * 0.125f;
      }
      float mp = s;
      #pragma unroll
      for (int mm = 32; mm; mm >>= 1) mp = fmaxf(mp, __shfl_xor(mp, mm));
      float p = (lane < 10) ? __expf(s - mp) : 0.f;
      float ps = p;
      #pragma unroll
      for (int mm = 32; mm; mm >>= 1) ps += __shfl_xor(ps, mm);
      float px = 0.f;
      #pragma unroll
      for (int j2 = 0; j2 < 10; j2++) px = fmaf(__shfl(p, j2), Pv[j2][lane], px);
      px = gh * px / ps;
      ao[(size_t)(b*513 + tok)*384 + h*64 + lane] = f2b(acc[i]/l_i[i] + px);
    }
  }
}

// ---------------------------------------------------------------------------
// Adapter (mid): xres = ad_gate*(h + gelu(h@Wd+bd)@Wu + bu) + xres. 1 block/row.
// ---------------------------------------------------------------------------
__global__ __launch_bounds__(256) void adapter_mid_kernel(const bf16* __restrict__ h,
    const bf16* __restrict__ Wd, const bf16* __restrict__ bd,
    const bf16* __restrict__ Wu, const bf16* __restrict__ bu,
    const bf16* __restrict__ p_gate, float* __restrict__ xres)
{
  __shared__ float s_h[384];
  __shared__ float s_part[16][17];
  __shared__ float s_y[16];
  const size_t row = blockIdx.x;
  const int t = threadIdx.x;
  const bf16* hp = h + row*384;
  for (int c = t; c < 384; c += 256) s_h[c] = b2f(hp[c]);
  __syncthreads();
  const int o = t & 15, p = t >> 4;
  float part0 = 0.f, part1 = 0.f;
  for (int c = p; c < 384; c += 32){
    part0 = fmaf(s_h[c],    b2f(Wd[(size_t)c*16 + o]),      part0);
    part1 = fmaf(s_h[c+16], b2f(Wd[(size_t)(c+16)*16 + o]), part1);
  }
  s_part[o][p] = part0 + part1;
  __syncthreads();
  if (t < 16){
    float sum = 0.f;
    #pragma unroll
    for (int pp = 0; pp < 16; pp++) sum += s_part[t][pp];
    s_y[t] = geluf(sum + b2f(bd[t]));
  }
  __syncthreads();
  const float g = b2f(p_gate[0]);
  for (int c = t; c < 384; c += 256){
    float up = 0.f;
    #pragma unroll
    for (int o2 = 0; o2 < 16; o2++) up = fmaf(s_y[o2], b2f(Wu[(size_t)o2*384 + c]), up);
    const float had = s_h[c] + up + b2f(bu[c]);
    xres[row*384 + c] = g*had + xres[row*384 + c];
  }
}

// ---------------------------------------------------------------------------
// Final adapter: out = xres + gelu(xres@Wd+bd)@Wu + bu. Output dtype per flag.
// ---------------------------------------------------------------------------
__global__ __launch_bounds__(256) void adapter_final_kernel(const float* __restrict__ xr,
    const bf16* __restrict__ Wd, const bf16* __restrict__ bd,
    const bf16* __restrict__ Wu, const bf16* __restrict__ bu,
    const int* __restrict__ flag, void* __restrict__ out)
{
  __shared__ float s_h[384];
  __shared__ float s_part[16][17];
  __shared__ float s_y[16];
  const size_t row = blockIdx.x;
  const int t = threadIdx.x;
  const float* hp = xr + row*384;
  for (int c = t; c < 384; c += 256) s_h[c] = hp[c];
  __syncthreads();
  const int o = t & 15, p = t >> 4;
  float part0 = 0.f, part1 = 0.f;
  for (int c = p; c < 384; c += 32){
    part0 = fmaf(s_h[c],    b2f(Wd[(size_t)c*16 + o]),      part0);
    part1 = fmaf(s_h[c+16], b2f(Wd[(size_t)(c+16)*16 + o]), part1);
  }
  s_part[o][p] = part0 + part1;
  __syncthreads();
  if (t < 16){
    float sum = 0.f;
    #pragma unroll
    for (int pp = 0; pp < 16; pp++) sum += s_part[t][pp];
    s_y[t] = geluf(sum + b2f(bd[t]));
  }
  __syncthreads();
  const bool isf = (*flag != 0);
  for (int c = t; c < 384; c += 256){
    float up = 0.f;
    #pragma unroll
    for (int o2 = 0; o2 < 16; o2++) up = fmaf(s_y[o2], b2f(Wu[(size_t)o2*384 + c]), up);
    const float v = s_h[c] + up + b2f(bu[c]);
    if (isf) ((float*)out)[row*384 + c] = v;
    else     ((bf16*)out)[row*384 + c] = f2b(v);
  }
}

// ---------------------------------------------------------------------------
// Fused local branch: one block (512 thr, 8 waves) per group of 32 tokens.
// gather -> LN3 -> per-head qkv -> 32x32 attention -> proj(+resid) ->
// max/mean pool -> BN -> GELU -> + center_cof * x_ct  => vis[group][384].
// ---------------------------------------------------------------------------
__global__ __launch_bounds__(512) void local_kernel(
    const float* __restrict__ xres, const int* __restrict__ idx, const int* __restrict__ cidx,
    const bf16* __restrict__ ln3g, const bf16* __restrict__ ln3b,
    const bf16* __restrict__ Wqkv1, const bf16* __restrict__ Wp1, const bf16* __restrict__ bp1,
    const bf16* __restrict__ bng, const bf16* __restrict__ bnb,
    const bf16* __restrict__ bnm, const bf16* __restrict__ bnv,
    const int* __restrict__ p_ifmm, const int* __restrict__ p_ccof,
    float* __restrict__ vis)
{
  __shared__ __align__(16) bf16 s_xln[32][384];
  __shared__ __align__(16) bf16 s_ao[32][384];
  __shared__ bf16 s_q[32][64];
  __shared__ bf16 s_k[32][66];
  __shared__ bf16 s_v[32][66];
  __shared__ int  s_tok[32];
  const int g = blockIdx.x;
  const int t = threadIdx.x, lane = t & 63, w = t >> 6;   // 8 waves, 4 rows each

  if (t < 32){
    const int r = idx[g*32 + t];                  // flat row in [0, 16384)
    s_tok[t] = (r >> 9)*513 + 1 + (r & 511);      // -> token row in xres
  }
  __syncthreads();

  // LN3 into s_xln
  #pragma unroll
  for (int i = 0; i < 4; i++){
    const int r = w*4 + i;
    const float* xp = xres + (size_t)s_tok[r]*384;
    float vv[6]; float s = 0.f, s2 = 0.f;
    #pragma unroll
    for (int c6 = 0; c6 < 6; c6++){ float x = xp[lane + 64*c6]; vv[c6] = x; s += x; s2 += x*x; }
    #pragma unroll
    for (int mm = 32; mm; mm >>= 1){ s += __shfl_xor(s, mm); s2 += __shfl_xor(s2, mm); }
    const float mean = s*(1.f/384.f);
    const float rs = rsqrtf(s2*(1.f/384.f) - mean*mean + 1e-5f);
    #pragma unroll
    for (int c6 = 0; c6 < 6; c6++){
      const int c = lane + 64*c6;
      s_xln[r][c] = f2b((vv[c6]-mean)*rs*b2f(ln3g[c]) + b2f(ln3b[c]));
    }
  }
  __syncthreads();

  for (int h = 0; h < 6; h++){
    float qa[4] = {0.f,0.f,0.f,0.f}, ka[4] = {0.f,0.f,0.f,0.f}, va[4] = {0.f,0.f,0.f,0.f};
    const bf16* wcol = Wqkv1 + h*64 + lane;
    #pragma unroll 2
    for (int c = 0; c < 384; c++){
      const float fq = b2f(wcol[(size_t)c*1152]);
      const float fk = b2f(wcol[(size_t)c*1152 + 384]);
      const float fv = b2f(wcol[(size_t)c*1152 + 768]);
      #pragma unroll
      for (int i = 0; i < 4; i++){
        const float xl = b2f(s_xln[w*4+i][c]);
        qa[i] = fmaf(xl, fq, qa[i]); ka[i] = fmaf(xl, fk, ka[i]); va[i] = fmaf(xl, fv, va[i]);
      }
    }
    #pragma unroll
    for (int i = 0; i < 4; i++){
      s_q[w*4+i][lane] = f2b(qa[i]); s_k[w*4+i][lane] = f2b(ka[i]); s_v[w*4+i][lane] = f2b(va[i]);
    }
    __syncthreads();

    #pragma unroll
    for (int pi = 0; pi < 2; pi++){
      const int rbase = w*4 + pi*2;
      const int r = rbase + (lane >> 5);
      const int j = lane & 31;
      float s0=0.f, s1=0.f, s2=0.f, s3=0.f;
      #pragma unroll 4
      for (int d = 0; d < 64; d += 4){
        s0 = fmaf(b2f(s_q[r][d+0]), b2f(s_k[j][d+0]), s0);
        s1 = fmaf(b2f(s_q[r][d+1]), b2f(s_k[j][d+1]), s1);
        s2 = fmaf(b2f(s_q[r][d+2]), b2f(s_k[j][d+2]), s2);
        s3 = fmaf(b2f(s_q[r][d+3]), b2f(s_k[j][d+3]), s3);
      }
      const float sdot = ((s0+s1)+(s2+s3)) * 0.125f;
      float mt = sdot;
      #pragma unroll
      for (int mm = 16; mm; mm >>= 1) mt = fmaxf(mt, __shfl_xor(mt, mm));
      float p = __expf(sdot - mt);
      float ps = p;
      #pragma unroll
      for (int mm = 16; mm; mm >>= 1) ps += __shfl_xor(ps, mm);
      p /= ps;
      #pragma unroll
      for (int rr = 0; rr < 2; rr++){
        float o0 = 0.f, o1 = 0.f;
        #pragma unroll 8
        for (int j2 = 0; j2 < 32; j2 += 2){
          o0 = fmaf(__shfl(p, rr*32 + j2),     b2f(s_v[j2][lane]),   o0);
          o1 = fmaf(__shfl(p, rr*32 + j2 + 1), b2f(s_v[j2+1][lane]), o1);
        }
        s_ao[rbase+rr][h*64 + lane] = f2b(o0 + o1);
      }
    }
    __syncthreads();
  }

  // proj (+resid +bias) and pooled epilogue; threads t<384 own one channel
  const float fmm  = scal(p_ifmm);
  const float ccof = scal(p_ccof);
  if (t < 384){
    float val[32];
    const float bp = b2f(bp1[t]);
    #pragma unroll
    for (int r = 0; r < 32; r++) val[r] = xres[(size_t)s_tok[r]*384 + t] + bp;
    for (int cb = 0; cb < 48; cb++){
      float wp[8];
      #pragma unroll
      for (int i = 0; i < 8; i++) wp[i] = b2f(Wp1[(size_t)(cb*8+i)*384 + t]);
      #pragma unroll
      for (int r = 0; r < 32; r++){
        uint4 u = *(const uint4*)&s_ao[r][cb*8];
        float a[8]; unp8(u, a);
        float d0 = fmaf(a[0], wp[0], fmaf(a[1], wp[1], 0.f));
        float d1 = fmaf(a[2], wp[2], fmaf(a[3], wp[3], 0.f));
        float d2 = fmaf(a[4], wp[4], fmaf(a[5], wp[5], 0.f));
        float d3 = fmaf(a[6], wp[6], fmaf(a[7], wp[7], 0.f));
        val[r] += (d0+d1)+(d2+d3);
      }
    }
    float vmax = -3e30f, vsum = 0.f;
    #pragma unroll
    for (int r = 0; r < 32; r++){ vmax = fmaxf(vmax, val[r]); vsum += val[r]; }
    const float lc = (fmm != 0.f) ? (vmax + vsum*(1.f/32.f)) : vmax;
    const float nr = (lc - b2f(bnm[t])) * rsqrtf(b2f(bnv[t]) + 1e-5f) * b2f(bng[t]) + b2f(bnb[t]);
    const int cr = cidx[g];
    const int ctok = (cr >> 9)*513 + 1 + (cr & 511);
    vis[(size_t)g*384 + t] = geluf(nr) + ccof * xres[(size_t)ctok*384 + t];
  }
}

// ---------------------------------------------------------------------------
// Inverse-distance interpolation: xt[b,n,:] += pro_cof * sum_s w[n,s] vis[b,s,:].
// ---------------------------------------------------------------------------
__global__ __launch_bounds__(256) void interp_kernel(const bf16* __restrict__ c1,
    const bf16* __restrict__ c2, const float* __restrict__ vis,
    const int* __restrict__ p_pcof, float* __restrict__ xres)
{
  __shared__ float s_w[8][128];
  __shared__ float s_red[2];
  const int b = blockIdx.y;
  const int n0 = blockIdx.x * 8;
  const int t = threadIdx.x;
  for (int ni = 0; ni < 8; ni++){
    const int n = n0 + ni;
    float wv = 0.f;
    if (t < 128){
      float d2 = 0.f;
      #pragma unroll
      for (int k = 0; k < 3; k++){
        const float a = b2f(c1[((size_t)b*512 + n)*3 + k]);
        const float c = b2f(c2[((size_t)b*128 + t)*3 + k]);
        const float df = a - c; d2 += df*df;
      }
      wv = 1.f/(d2 + 1e-8f);
    }
    float rsum = wv;
    #pragma unroll
    for (int mm = 32; mm; mm >>= 1) rsum += __shfl_xor(rsum, mm);
    if (((t & 63) == 0) && t < 128) s_red[t >> 6] = rsum;
    __syncthreads();
    const float tot = s_red[0] + s_red[1];
    if (t < 128) s_w[ni][t] = wv / tot;
    __syncthreads();
  }
  float acc1[8], acc2[8];
  #pragma unroll
  for (int ni = 0; ni < 8; ni++){ acc1[ni] = 0.f; acc2[ni] = 0.f; }
  for (int s = 0; s < 128; s++){
    const float* vp = vis + ((size_t)b*128 + s)*384;
    const float v1 = vp[t];
    const float v2 = (t < 128) ? vp[t + 256] : 0.f;
    #pragma unroll
    for (int ni = 0; ni < 8; ni++){
      const float wn = s_w[ni][s];
      acc1[ni] = fmaf(wn, v1, acc1[ni]);
      acc2[ni] = fmaf(wn, v2, acc2[ni]);
    }
  }
  const float pc = scal(p_pcof);
  #pragma unroll
  for (int ni = 0; ni < 8; ni++){
    const int tok = b*513 + 1 + n0 + ni;
    xres[(size_t)tok*384 + t] += pc*acc1[ni];
    if (t < 128) xres[(size_t)tok*384 + t + 256] += pc*acc2[ni];
  }
}

// ---------------------------------------------------------------------------
extern "C" void kernel_launch(void* const* d_in, const int* in_sizes, int n_in,
                              void* d_out, int out_size, void* d_ws, size_t ws_size,
                              hipStream_t stream)
{
  (void)n_in; (void)out_size; (void)ws_size;
  const int*  idx   = (const int*)d_in[35];
  const int*  cidx  = (const int*)d_in[36];
  // d_in[37] = group_size (fixed 32)
  const int*  ifmm  = (const int*)d_in[38];
  const int*  pcof  = (const int*)d_in[39];
  const int*  ccof  = (const int*)d_in[40];

  // Workspace layout (~93 MB):
  //   flag   int                              256 B
  //   xres   f32  [TOK,384]                   25,214,976 B
  //   slab   bf16 [TOK,1536]                  50,429,952 B
  //          phase A: qkv = slab[0 : TOK*1152), canonical-x = slab[TOK*1152 : TOK*1536)
  //          phase B: h1  = slab[0 : TOK*1536)   (x dead after proj-resid)
  //          phase C: vis = (f32)slab[0 : 4096*384)
  //   xn     bf16 [TOK,384]: ln1 -> ao -> ln2 -> h   12,607,488 B
  //   pq     f32  [10,1152]                   46,080 B
  //   canon  bf16 weights/smalls              ~4.92 MB
  size_t off = 0;
  auto alloc = [&](size_t bytes) -> void* {
    void* p = (char*)d_ws + off; off += (bytes + 255) & ~(size_t)255; return p;
  };
  int*   flag = (int*)  alloc(sizeof(int));
  float* xres = (float*)alloc((size_t)TOK*384*4);
  bf16*  slab = (bf16*) alloc((size_t)TOK*1536*2);
  bf16*  xn   = (bf16*) alloc((size_t)TOK*384*2);
  float* pq   = (float*)alloc((size_t)10*1152*4);

  bf16*  qkvb = slab;
  bf16*  x_c  = slab + (size_t)TOK*1152;   // canonical x overlays future-h1 tail
  bf16*  h1   = slab;
  float* visb = (float*)slab;
  bf16*  ao   = xn;
  bf16*  hbuf = xn;

  // canonical bf16 copies of all float inputs (skip [3]=neighborhood, ints)
  const int conv_ids[34] = {0,1,2,4,5,6,7,8,9,10,11,12,13,14,15,16,17,
                            18,19,20,21,22,23,24,25,26,27,28,29,30,31,32,33,34};
  ConvArgs ca;
  bf16* canon[41];
  int maxn = 1;
  for (int k = 0; k < 34; k++){
    const int i = conv_ids[k];
    const int n = in_sizes[i];
    bf16* dst = (i == 0) ? x_c : (bf16*)alloc((size_t)n*2);
    ca.src[k] = d_in[i]; ca.dst[k] = dst; ca.n[k] = n;
    canon[i] = dst;
    if (n > maxn) maxn = n;
  }
  // 0a. detect input dtype (fp32 vs bf16) from x
  detect_kernel<<<dim3(1), dim3(256), 0, stream>>>((const unsigned*)d_in[0], flag);
  // 0b. canonicalize all float inputs to bf16
  {
    int gx = (maxn + 256*64 - 1) / (256*64); if (gx > 64) gx = 64; if (gx < 1) gx = 1;
    convert_many<<<dim3(gx, 34), dim3(256), 0, stream>>>(flag, ca);
  }

  const bf16 *x_in = canon[0], *c1 = canon[1], *c2 = canon[2], *pe = canon[4],
             *ln1g = canon[5], *ln1b = canon[6], *Wqkv = canon[7], *Wproj = canon[8],
             *bproj = canon[9], *gate = canon[10], *ln2g = canon[11], *ln2b = canon[12],
             *W1 = canon[13], *b1 = canon[14], *W2 = canon[15], *b2v = canon[16],
             *adW = canon[17], *adb = canon[18], *adU = canon[19], *adub = canon[20],
             *adg = canon[21], *bng = canon[22], *bnb = canon[23], *bnm = canon[24],
             *bnv = canon[25], *ln3g = canon[26], *ln3b = canon[27], *a1W = canon[28],
             *a1P = canon[29], *a1pb = canon[30], *d1W = canon[31], *d1b = canon[32],
             *u1W = canon[33], *u1b = canon[34];

  // 1. LN1: x -> xn (bf16)
  ln_kernel<true><<<dim3((TOK*64)/256), dim3(256), 0, stream>>>((const void*)x_in, ln1g, ln1b, xn, TOK);
  // 2. qkv = xn @ Wqkv (bf16)
  gemm_kernel<1><<<dim3(18,129), dim3(256), 0, stream>>>(xn, Wqkv, nullptr, nullptr, qkvb, TOK, 1152, 384);
  // 2b. prompt qkv (no LN on prompt)
  pqkv_kernel<<<dim3(18), dim3(256), 0, stream>>>(pe, Wqkv, pq);
  // 3. attention (+ prompt cross-attn) -> ao (bf16, reuses xn)
  attn_kernel<<<dim3(17,192), dim3(256), 0, stream>>>(qkvb, pq, gate, ao);
  // 4. xres = x + ao @ Wproj + bproj  (f32)
  gemm_kernel<3><<<dim3(6,129), dim3(256), 0, stream>>>(ao, Wproj, bproj, x_in, xres, TOK, 384, 384);
  // 5. LN2: xres -> xn (bf16)
  ln_kernel<false><<<dim3((TOK*64)/256), dim3(256), 0, stream>>>((const void*)xres, ln2g, ln2b, xn, TOK);
  // 6. h1 = gelu(xn @ W1 + b1) (bf16, into slab; qkv and canonical-x dead)
  gemm_kernel<2><<<dim3(24,129), dim3(256), 0, stream>>>(xn, W1, b1, nullptr, h1, TOK, 1536, 384);
  // 7. h = h1 @ W2 + b2 (bf16, into xn; LN2 out dead)
  gemm_kernel<0><<<dim3(6,129), dim3(256), 0, stream>>>(h1, W2, b2v, nullptr, hbuf, TOK, 384, 1536);
  // 8. xres = ad_gate*(h + adapter(h)) + xres
  adapter_mid_kernel<<<dim3(TOK), dim3(256), 0, stream>>>(hbuf, adW, adb, adU, adub, adg, xres);
  // 9. fused local branch -> vis (f32, into slab; h1 dead)
  local_kernel<<<dim3(4096), dim3(512), 0, stream>>>(xres, idx, cidx, ln3g, ln3b, a1W, a1P, a1pb,
                                                     bng, bnb, bnm, bnv, ifmm, ccof, visb);
  // 10. xt += pro_cof * interp(w, vis)
  interp_kernel<<<dim3(64,32), dim3(256), 0, stream>>>(c1, c2, visb, pcof, xres);
  // 11. final adapter -> d_out (dtype per flag)
  adapter_final_kernel<<<dim3(TOK), dim3(256), 0, stream>>>(xres, d1W, d1b, u1W, u1b, flag, d_out);
}

// Round 4
// 2958.251 us; speedup vs baseline: 2.4097x; 2.4097x over previous
//
#include <hip/hip_runtime.h>
#include <hip/hip_bf16.h>
#include <cstdint>
#include <cstddef>

// Problem constants: B=32, G=512, S=128, GS=32, P=10, C=384, H=6, D=64,
// HID=1536, RED=16, tokens per batch = 513.
typedef __hip_bfloat16 bf16;
constexpr int TOK = 32 * 513;   // 16416 rows in the residual stream

typedef __attribute__((ext_vector_type(8))) short short8;
typedef __attribute__((ext_vector_type(4))) float f32x4;

__device__ __forceinline__ float bflo(unsigned u){ return __uint_as_float(u << 16); }
__device__ __forceinline__ float bfhi(unsigned u){ return __uint_as_float(u & 0xffff0000u); }
__device__ __forceinline__ float b2f(bf16 x){ return __bfloat162float(x); }
__device__ __forceinline__ bf16  f2b(float x){ return __float2bfloat16(x); }
__device__ __forceinline__ float geluf(float x){ return 0.5f*x*(1.0f + erff(x*0.70710678118654752f)); }
__device__ __forceinline__ void unp8(uint4 u, float* f){
  f[0]=bflo(u.x); f[1]=bfhi(u.x); f[2]=bflo(u.y); f[3]=bfhi(u.y);
  f[4]=bflo(u.z); f[5]=bfhi(u.z); f[6]=bflo(u.w); f[7]=bfhi(u.w);
}
// Scalar decode robust to int32-vs-float32 materialization of Python scalars.
__device__ __forceinline__ float scal(const int* p){
  const int i = *p;
  if (i > -1000000 && i < 1000000) return (float)i;
  return __int_as_float(i);
}
__device__ __forceinline__ f32x4 mfma16(short8 a, short8 b, f32x4 c){
  return __builtin_amdgcn_mfma_f32_16x16x32_bf16(a, b, c, 0, 0, 0);
}

// ---------------------------------------------------------------------------
// Dtype detection: if any 16-bit half of x's first 2048 words, viewed as bf16,
// is NaN or |v|>1e6 => inputs are fp32 (flag=1). bf16 inputs (|x|<~6) => 0.
// ---------------------------------------------------------------------------
__global__ __launch_bounds__(256) void detect_kernel(const unsigned* __restrict__ x,
                                                     int* __restrict__ flag)
{
  const int t = threadIdx.x;
  bool bad = false;
  for (int i = t; i < 2048; i += 256){
    const unsigned u = x[i];
    const float a = fabsf(bflo(u)), b = fabsf(bfhi(u));
    if (!(a < 1e6f) || !(b < 1e6f)) bad = true;   // NaN fails the compare
  }
  __shared__ int s;
  if (t == 0) s = 0;
  __syncthreads();
  const unsigned long long m = __ballot(bad);
  if (m != 0ull && (t & 63) == 0) atomicOr(&s, 1);
  __syncthreads();
  if (t == 0) *flag = s;
}

// ---------------------------------------------------------------------------
// Canonicalize all float inputs to bf16 (copy if already bf16).
// ---------------------------------------------------------------------------
struct ConvArgs {
  const void* src[34];
  bf16*       dst[34];
  int         n[34];
};
__global__ __launch_bounds__(256) void convert_many(const int* __restrict__ flag, ConvArgs a)
{
  const int ii = blockIdx.y;
  const bool isf = (*flag != 0);
  const int n = a.n[ii];
  const void* s = a.src[ii];
  bf16* d = a.dst[ii];
  for (int i = blockIdx.x*256 + threadIdx.x; i < n; i += gridDim.x*256){
    d[i] = isf ? f2b(((const float*)s)[i]) : ((const bf16*)s)[i];
  }
}

// ---------------------------------------------------------------------------
// Shuffle weight W[K x N] (row-major) into MFMA B-fragment order:
// out[(((n0*KT + k0)*64 + lane)*8 + j] = W[(k0*32 + (lane>>4)*8 + j)*N + n0*16 + (lane&15)]
// so a lane's 8 B-frag values are one 16B coalesced load.
// ---------------------------------------------------------------------------
__global__ __launch_bounds__(256) void shuffle_b(const bf16* __restrict__ W,
    bf16* __restrict__ out, int N, int KT, int NT)
{
  const int id = blockIdx.x*256 + threadIdx.x;
  if (id >= NT*KT*64) return;
  const int l  = id & 63;
  const int k0 = (id >> 6) % KT;
  const int n0 = (id >> 6) / KT;
  bf16 tmp[8];
  #pragma unroll
  for (int j = 0; j < 8; j++)
    tmp[j] = W[(size_t)(k0*32 + (l>>4)*8 + j)*N + n0*16 + (l&15)];
  *(uint4*)(out + (size_t)id*8) = *(const uint4*)tmp;
}

// ---------------------------------------------------------------------------
// LayerNorm: one wave per row of 384. Output bf16.
// ---------------------------------------------------------------------------
template<bool SRC_BF16>
__global__ __launch_bounds__(256) void ln_kernel(const void* __restrict__ src,
    const bf16* __restrict__ g, const bf16* __restrict__ b,
    bf16* __restrict__ out, int rows)
{
  const int wave = (blockIdx.x * blockDim.x + threadIdx.x) >> 6;
  const int lane = threadIdx.x & 63;
  if (wave >= rows) return;
  float v[6]; float s = 0.f, s2 = 0.f;
  #pragma unroll
  for (int i = 0; i < 6; i++){
    const int c = lane + 64*i;
    float x;
    if (SRC_BF16) x = b2f(((const bf16*)src)[(size_t)wave*384 + c]);
    else          x = ((const float*)src)[(size_t)wave*384 + c];
    v[i] = x; s += x; s2 += x*x;
  }
  #pragma unroll
  for (int mm = 32; mm; mm >>= 1){ s += __shfl_xor(s, mm); s2 += __shfl_xor(s2, mm); }
  const float mean = s * (1.f/384.f);
  const float rs = rsqrtf(s2 * (1.f/384.f) - mean*mean + 1e-5f);
  #pragma unroll
  for (int i = 0; i < 6; i++){
    const int c = lane + 64*i;
    out[(size_t)wave*384 + c] = f2b((v[i]-mean)*rs*b2f(g[c]) + b2f(b[c]));
  }
}

// ---------------------------------------------------------------------------
// Tiled GEMM (fp32 VALU): out[M,N] = A[M,K] @ W[K,N] (+bias, epilogue). A bf16.
// EPI: 0 = bf16 out, +bias; 1 = bf16 out; 2 = bf16 out gelu(+bias);
//      3 = f32 out, +bias +bf16resid
// ---------------------------------------------------------------------------
template<int EPI>
__global__ __launch_bounds__(256) void gemm_kernel(
    const bf16* __restrict__ A, const bf16* __restrict__ W,
    const bf16* __restrict__ bias, const bf16* __restrict__ resid,
    void* __restrict__ outv, int M, int N, int K)
{
  __shared__ float As[16][129];   // [k][m], +1 pad
  __shared__ float Ws[16][64];    // [k][n]
  const int t  = threadIdx.x;
  const int m0 = blockIdx.y * 128;
  const int n0 = blockIdx.x * 64;
  const int tx = t & 15, ty = t >> 4;
  float acc[8][4];
  #pragma unroll
  for (int i = 0; i < 8; i++){
    #pragma unroll
    for (int j = 0; j < 4; j++) acc[i][j] = 0.f;
  }
  const int ar  = t >> 1;
  const int kc  = (t & 1) * 8;
  const int wkr = t >> 4;
  const int wnc = (t & 15) * 4;

  for (int k0 = 0; k0 < K; k0 += 16){
    float av[8];
    const int gm = m0 + ar;
    if (gm < M){
      uint4 u = *(const uint4*)(A + (size_t)gm*K + k0 + kc);
      unp8(u, av);
    } else {
      #pragma unroll
      for (int i = 0; i < 8; i++) av[i] = 0.f;
    }
    #pragma unroll
    for (int i = 0; i < 8; i++) As[kc+i][ar] = av[i];
    {
      uint2 u = *(const uint2*)(W + (size_t)(k0+wkr)*N + n0 + wnc);
      Ws[wkr][wnc+0]=bflo(u.x); Ws[wkr][wnc+1]=bfhi(u.x);
      Ws[wkr][wnc+2]=bflo(u.y); Ws[wkr][wnc+3]=bfhi(u.y);
    }
    __syncthreads();
    #pragma unroll
    for (int kk = 0; kk < 16; kk++){
      float a[8];
      #pragma unroll
      for (int i = 0; i < 8; i++) a[i] = As[kk][ty*8+i];
      float4 wb = *(const float4*)&Ws[kk][tx*4];
      #pragma unroll
      for (int i = 0; i < 8; i++){
        acc[i][0] = fmaf(a[i], wb.x, acc[i][0]);
        acc[i][1] = fmaf(a[i], wb.y, acc[i][1]);
        acc[i][2] = fmaf(a[i], wb.z, acc[i][2]);
        acc[i][3] = fmaf(a[i], wb.w, acc[i][3]);
      }
    }
    __syncthreads();
  }
  const int gn0 = n0 + tx*4;
  #pragma unroll
  for (int i = 0; i < 8; i++){
    const int gm = m0 + ty*8 + i;
    if (gm < M){
      #pragma unroll
      for (int j = 0; j < 4; j++){
        float v = acc[i][j];
        const int gn = gn0 + j;
        const size_t o = (size_t)gm*N + gn;
        if (EPI == 0){ v += b2f(bias[gn]); ((bf16*)outv)[o] = f2b(v); }
        else if (EPI == 1){ ((bf16*)outv)[o] = f2b(v); }
        else if (EPI == 2){ v += b2f(bias[gn]); ((bf16*)outv)[o] = f2b(geluf(v)); }
        else { v += b2f(bias[gn]) + b2f(resid[o]); ((float*)outv)[o] = v; }
      }
    }
  }
}

// ---------------------------------------------------------------------------
// Prompt QKV: (10 x 384) @ (384 x 1152) -> f32 (prompt used WITHOUT LN).
// ---------------------------------------------------------------------------
__global__ __launch_bounds__(256) void pqkv_kernel(const bf16* __restrict__ pe,
    const bf16* __restrict__ Wqkv, float* __restrict__ pq)
{
  const int n  = blockIdx.x*64 + (threadIdx.x & 63);
  const int rg = threadIdx.x >> 6;
  for (int r = rg; r < 10; r += 4){
    float s0 = 0.f, s1 = 0.f;
    for (int c = 0; c < 384; c += 2){
      s0 = fmaf(b2f(pe[(size_t)r*384+c]),   b2f(Wqkv[(size_t)c*1152 + n]),     s0);
      s1 = fmaf(b2f(pe[(size_t)r*384+c+1]), b2f(Wqkv[(size_t)(c+1)*1152 + n]), s1);
    }
    pq[(size_t)r*1152 + n] = s0 + s1;
  }
}

// ---------------------------------------------------------------------------
// Main attention (513 keys, flash-style) + prompt cross-attention fused.
// grid = (17 q-chunks of 32 rows, 192 b*h). 256 threads = 4 waves x 8 rows.
// ---------------------------------------------------------------------------
__global__ __launch_bounds__(256) void attn_kernel(
    const bf16* __restrict__ qkv, const float* __restrict__ pq,
    const bf16* __restrict__ gate, bf16* __restrict__ ao)
{
  __shared__ float KtT[64][65];
  __shared__ float Vt[64][65];
  __shared__ float Qr[32][64];
  __shared__ float Pk[10][65];
  __shared__ float Pv[10][65];
  const int bh = blockIdx.y;
  const int b = bh / 6, h = bh % 6;
  const int r0 = blockIdx.x * 32;
  const int t = threadIdx.x;
  const int lane = t & 63;
  const int w = t >> 6;

  {
    const int rr = t >> 3, dc = (t & 7) * 8;
    const int tok = r0 + rr;
    float f[8];
    if (tok < 513){
      uint4 u = *(const uint4*)(qkv + (size_t)(b*513 + tok)*1152 + h*64 + dc);
      unp8(u, f);
    } else {
      #pragma unroll
      for (int i = 0; i < 8; i++) f[i] = 0.f;
    }
    #pragma unroll
    for (int i = 0; i < 8; i++) Qr[rr][dc+i] = f[i];
  }
  if (t < 160){
    const int j = t >> 4, dc = (t & 15) * 4;
    const float* pk = pq + (size_t)j*1152 + 384 + h*64 + dc;
    const float* pv = pq + (size_t)j*1152 + 768 + h*64 + dc;
    #pragma unroll
    for (int i = 0; i < 4; i++){ Pk[j][dc+i] = pk[i]; Pv[j][dc+i] = pv[i]; }
  }
  __syncthreads();

  float m_i[8], l_i[8], acc[8];
  #pragma unroll
  for (int i = 0; i < 8; i++){ m_i[i] = -30000.f; l_i[i] = 0.f; acc[i] = 0.f; }

  for (int kt = 0; kt < 9; kt++){
    const int kb = kt * 64;
    {
      const int j = t >> 2, dc = (t & 3) * 16;
      const int tok = kb + j;
      float fk[16], fv[16];
      if (tok < 513){
        const bf16* base = qkv + (size_t)(b*513 + tok)*1152 + h*64 + dc;
        unp8(*(const uint4*)(base + 384), fk);
        unp8(*(const uint4*)(base + 392), fk + 8);
        unp8(*(const uint4*)(base + 768), fv);
        unp8(*(const uint4*)(base + 776), fv + 8);
      } else {
        #pragma unroll
        for (int i = 0; i < 16; i++){ fk[i] = 0.f; fv[i] = 0.f; }
      }
      #pragma unroll
      for (int i = 0; i < 16; i++){ KtT[dc+i][j] = fk[i]; Vt[j][dc+i] = fv[i]; }
    }
    __syncthreads();
    const int nv = (513 - kb < 64) ? (513 - kb) : 64;
    for (int i = 0; i < 8; i++){
      const int r = w*8 + i;
      if (r0 + r < 513){
        float s = -30000.f;
        if (lane < nv){
          float s0=0.f, s1=0.f, s2=0.f, s3=0.f;
          #pragma unroll 4
          for (int d = 0; d < 64; d += 4){
            s0 = fmaf(Qr[r][d+0], KtT[d+0][lane], s0);
            s1 = fmaf(Qr[r][d+1], KtT[d+1][lane], s1);
            s2 = fmaf(Qr[r][d+2], KtT[d+2][lane], s2);
            s3 = fmaf(Qr[r][d+3], KtT[d+3][lane], s3);
          }
          s = ((s0+s1)+(s2+s3)) * 0.125f;
        }
        float mt = s;
        #pragma unroll
        for (int mm = 32; mm; mm >>= 1) mt = fmaxf(mt, __shfl_xor(mt, mm));
        const float mn = fmaxf(m_i[i], mt);
        const float al = __expf(m_i[i] - mn);
        float p = (lane < nv) ? __expf(s - mn) : 0.f;
        float ps = p;
        #pragma unroll
        for (int mm = 32; mm; mm >>= 1) ps += __shfl_xor(ps, mm);
        l_i[i] = l_i[i]*al + ps;
        m_i[i] = mn;
        float a0 = acc[i]*al, a1 = 0.f;
        #pragma unroll 8
        for (int j2 = 0; j2 < 64; j2 += 2){
          a0 = fmaf(__shfl(p, j2),   Vt[j2][lane],   a0);
          a1 = fmaf(__shfl(p, j2+1), Vt[j2+1][lane], a1);
        }
        acc[i] = a0 + a1;
      }
    }
    __syncthreads();
  }

  const float gh = b2f(gate[h]);
  for (int i = 0; i < 8; i++){
    const int r = w*8 + i;
    const int tok = r0 + r;
    if (tok < 513){
      float s = -30000.f;
      if (lane < 10){
        float s0=0.f, s1=0.f;
        #pragma unroll 8
        for (int d = 0; d < 64; d += 2){
          s0 = fmaf(Qr[r][d],   Pk[lane][d],   s0);
          s1 = fmaf(Qr[r][d+1], Pk[lane][d+1], s1);
        }
        s = (s0+s1) * 0.125f;
      }
      float mp = s;
      #pragma unroll
      for (int mm = 32; mm; mm >>= 1) mp = fmaxf(mp, __shfl_xor(mp, mm));
      float p = (lane < 10) ? __expf(s - mp) : 0.f;
      float ps = p;
      #pragma unroll
      for (int mm = 32; mm; mm >>= 1) ps += __shfl_xor(ps, mm);
      float px = 0.f;
      #pragma unroll
      for (int j2 = 0; j2 < 10; j2++) px = fmaf(__shfl(p, j2), Pv[j2][lane], px);
      px = gh * px / ps;
      ao[(size_t)(b*513 + tok)*384 + h*64 + lane] = f2b(acc[i]/l_i[i] + px);
    }
  }
}

// ---------------------------------------------------------------------------
// Adapter (mid): xres = ad_gate*(h + gelu(h@Wd+bd)@Wu + bu) + xres. 1 block/row.
// ---------------------------------------------------------------------------
__global__ __launch_bounds__(256) void adapter_mid_kernel(const bf16* __restrict__ h,
    const bf16* __restrict__ Wd, const bf16* __restrict__ bd,
    const bf16* __restrict__ Wu, const bf16* __restrict__ bu,
    const bf16* __restrict__ p_gate, float* __restrict__ xres)
{
  __shared__ float s_h[384];
  __shared__ float s_part[16][17];
  __shared__ float s_y[16];
  const size_t row = blockIdx.x;
  const int t = threadIdx.x;
  const bf16* hp = h + row*384;
  for (int c = t; c < 384; c += 256) s_h[c] = b2f(hp[c]);
  __syncthreads();
  const int o = t & 15, p = t >> 4;
  float part0 = 0.f, part1 = 0.f;
  for (int c = p; c < 384; c += 32){
    part0 = fmaf(s_h[c],    b2f(Wd[(size_t)c*16 + o]),      part0);
    part1 = fmaf(s_h[c+16], b2f(Wd[(size_t)(c+16)*16 + o]), part1);
  }
  s_part[o][p] = part0 + part1;
  __syncthreads();
  if (t < 16){
    float sum = 0.f;
    #pragma unroll
    for (int pp = 0; pp < 16; pp++) sum += s_part[t][pp];
    s_y[t] = geluf(sum + b2f(bd[t]));
  }
  __syncthreads();
  const float g = b2f(p_gate[0]);
  for (int c = t; c < 384; c += 256){
    float up = 0.f;
    #pragma unroll
    for (int o2 = 0; o2 < 16; o2++) up = fmaf(s_y[o2], b2f(Wu[(size_t)o2*384 + c]), up);
    const float had = s_h[c] + up + b2f(bu[c]);
    xres[row*384 + c] = g*had + xres[row*384 + c];
  }
}

// ---------------------------------------------------------------------------
// Final adapter: out = xres + gelu(xres@Wd+bd)@Wu + bu. Output dtype per flag.
// ---------------------------------------------------------------------------
__global__ __launch_bounds__(256) void adapter_final_kernel(const float* __restrict__ xr,
    const bf16* __restrict__ Wd, const bf16* __restrict__ bd,
    const bf16* __restrict__ Wu, const bf16* __restrict__ bu,
    const int* __restrict__ flag, void* __restrict__ out)
{
  __shared__ float s_h[384];
  __shared__ float s_part[16][17];
  __shared__ float s_y[16];
  const size_t row = blockIdx.x;
  const int t = threadIdx.x;
  const float* hp = xr + row*384;
  for (int c = t; c < 384; c += 256) s_h[c] = hp[c];
  __syncthreads();
  const int o = t & 15, p = t >> 4;
  float part0 = 0.f, part1 = 0.f;
  for (int c = p; c < 384; c += 32){
    part0 = fmaf(s_h[c],    b2f(Wd[(size_t)c*16 + o]),      part0);
    part1 = fmaf(s_h[c+16], b2f(Wd[(size_t)(c+16)*16 + o]), part1);
  }
  s_part[o][p] = part0 + part1;
  __syncthreads();
  if (t < 16){
    float sum = 0.f;
    #pragma unroll
    for (int pp = 0; pp < 16; pp++) sum += s_part[t][pp];
    s_y[t] = geluf(sum + b2f(bd[t]));
  }
  __syncthreads();
  const bool isf = (*flag != 0);
  for (int c = t; c < 384; c += 256){
    float up = 0.f;
    #pragma unroll
    for (int o2 = 0; o2 < 16; o2++) up = fmaf(s_y[o2], b2f(Wu[(size_t)o2*384 + c]), up);
    const float v = s_h[c] + up + b2f(bu[c]);
    if (isf) ((float*)out)[row*384 + c] = v;
    else     ((bf16*)out)[row*384 + c] = f2b(v);
  }
}

// ---------------------------------------------------------------------------
// Fused local branch (MFMA version): one block (512 thr, 8 waves) per group.
// gather -> LN3 -> MFMA QKV (shuffled Bq) -> MFMA 32x32 attention ->
// MFMA proj accumulated per-head (shuffled Bp) -> pool/BN/GELU -> vis.
// MFMA layouts (m89/m91-verified): A[m=lane&15][k=quad*8+j],
// B[k=quad*8+j][n=lane&15], D[row=quad*4+reg][col=lane&15].
// ---------------------------------------------------------------------------
__global__ __launch_bounds__(512) void local_kernel(
    const float* __restrict__ xres, const int* __restrict__ idx, const int* __restrict__ cidx,
    const bf16* __restrict__ ln3g, const bf16* __restrict__ ln3b,
    const bf16* __restrict__ Bq, const bf16* __restrict__ Bp, const bf16* __restrict__ bp1,
    const bf16* __restrict__ bng, const bf16* __restrict__ bnb,
    const bf16* __restrict__ bnm, const bf16* __restrict__ bnv,
    const int* __restrict__ p_ifmm, const int* __restrict__ p_ccof,
    float* __restrict__ vis)
{
  // strides padded to 16B multiples; >=stride-4 word offsets => <=2-way bank alias (free)
  __shared__ __align__(16) bf16  s_xln[32*392];  // X after LN3, row stride 392
  __shared__ __align__(16) bf16  s_q[32*72];     // Q, then O (per head)
  __shared__ __align__(16) bf16  s_k[32*72];     // K
  __shared__ __align__(16) bf16  s_vT[64*40];    // V transposed [d][tok]
  __shared__ __align__(16) float s_S[32*33];     // scores f32
  __shared__ __align__(16) bf16  s_p[32*40];     // softmax probs
  __shared__ int s_tok[32];

  const int g = blockIdx.x;
  const int t = threadIdx.x, lane = t & 63, w = t >> 6;
  const int l15 = lane & 15, quad = lane >> 4;

  if (t < 32){
    const int r = idx[g*32 + t];                  // flat row in [0, 16384)
    s_tok[t] = (r >> 9)*513 + 1 + (r & 511);      // -> token row in xres
  }
  __syncthreads();

  // LN3 into s_xln: 8 waves x 4 rows
  #pragma unroll
  for (int i = 0; i < 4; i++){
    const int r = w*4 + i;
    const float* xp = xres + (size_t)s_tok[r]*384;
    float vv[6]; float s = 0.f, s2 = 0.f;
    #pragma unroll
    for (int c6 = 0; c6 < 6; c6++){ float x = xp[lane + 64*c6]; vv[c6] = x; s += x; s2 += x*x; }
    #pragma unroll
    for (int mm = 32; mm; mm >>= 1){ s += __shfl_xor(s, mm); s2 += __shfl_xor(s2, mm); }
    const float mean = s*(1.f/384.f);
    const float rs = rsqrtf(s2*(1.f/384.f) - mean*mean + 1e-5f);
    #pragma unroll
    for (int c6 = 0; c6 < 6; c6++){
      const int c = lane + 64*c6;
      s_xln[r*392 + c] = f2b((vv[c6]-mean)*rs*b2f(ln3g[c]) + b2f(ln3b[c]));
    }
  }
  __syncthreads();

  // persistent proj accumulators: 3 n-tiles x 2 m-tiles per wave
  f32x4 accp[3][2];
  #pragma unroll
  for (int a = 0; a < 3; a++){
    #pragma unroll
    for (int m = 0; m < 2; m++) accp[a][m] = f32x4{0.f,0.f,0.f,0.f};
  }

  for (int h = 0; h < 6; h++){
    // ---- QKV for head h: 24 tiles (2 mt x 12 j); wave w takes ids {w, w+8, w+16}
    #pragma unroll
    for (int tt = 0; tt < 3; tt++){
      const int id = w + tt*8;
      const int mt = id / 12, j = id % 12;
      const int grp = j >> 2, jc = j & 3;                 // 0=Q,1=K,2=V
      const int gnt = grp*24 + h*4 + jc;                  // global n-tile in Wqkv
      f32x4 acc = f32x4{0.f,0.f,0.f,0.f};
      const short8* ap = (const short8*)(s_xln + (mt*16 + l15)*392);
      const bf16* bptr = Bq + ((size_t)(gnt*12)*64 + lane)*8;
      #pragma unroll 4
      for (int k0 = 0; k0 < 12; k0++){
        const short8 a = ap[k0*4 + quad];
        const short8 b = *(const short8*)(bptr + (size_t)k0*64*8);
        acc = mfma16(a, b, acc);
      }
      #pragma unroll
      for (int r = 0; r < 4; r++){
        const int tok = mt*16 + quad*4 + r;
        const bf16 v = f2b(acc[r]);
        if (grp == 0)      s_q[tok*72 + jc*16 + l15] = v;
        else if (grp == 1) s_k[tok*72 + jc*16 + l15] = v;
        else               s_vT[(jc*16 + l15)*40 + tok] = v;
      }
    }
    __syncthreads();

    // ---- S = (Q K^T) * scale : 4 tiles on waves 0..3
    if (w < 4){
      const int mt = w & 1, nt = w >> 1;
      f32x4 acc = f32x4{0.f,0.f,0.f,0.f};
      const short8* ap = (const short8*)(s_q + (mt*16 + l15)*72);
      const short8* bp = (const short8*)(s_k + (nt*16 + l15)*72);
      #pragma unroll
      for (int k0 = 0; k0 < 2; k0++)
        acc = mfma16(ap[k0*4 + quad], bp[k0*4 + quad], acc);
      #pragma unroll
      for (int r = 0; r < 4; r++)
        s_S[(mt*16 + quad*4 + r)*33 + nt*16 + l15] = acc[r]*0.125f;
    }
    __syncthreads();

    // ---- softmax: 16 threads/row, 2 cols each
    {
      const int row = t >> 4, col = t & 15;
      const float v0 = s_S[row*33 + col], v1 = s_S[row*33 + col + 16];
      float mx = fmaxf(v0, v1);
      #pragma unroll
      for (int mm = 8; mm; mm >>= 1) mx = fmaxf(mx, __shfl_xor(mx, mm));
      const float e0 = __expf(v0 - mx), e1 = __expf(v1 - mx);
      float sm = e0 + e1;
      #pragma unroll
      for (int mm = 8; mm; mm >>= 1) sm += __shfl_xor(sm, mm);
      const float inv = 1.f/sm;
      s_p[row*40 + col]      = f2b(e0*inv);
      s_p[row*40 + col + 16] = f2b(e1*inv);
    }
    __syncthreads();

    // ---- O = P V : 8 tiles (mt=w&1, nt=w>>1), K=32, writes O over s_q
    {
      const int mt = w & 1, nt = w >> 1;
      const short8 a = *(const short8*)(s_p + (mt*16 + l15)*40 + quad*8);
      const short8 b = *(const short8*)(s_vT + (nt*16 + l15)*40 + quad*8);
      f32x4 acc = mfma16(a, b, f32x4{0.f,0.f,0.f,0.f});
      #pragma unroll
      for (int r = 0; r < 4; r++)
        s_q[(mt*16 + quad*4 + r)*72 + nt*16 + l15] = f2b(acc[r]);
    }
    __syncthreads();

    // ---- proj partial: acc += O_h @ Wp[h*64:(h+1)*64, :]
    #pragma unroll
    for (int tt = 0; tt < 3; tt++){
      const int nt = w*3 + tt;
      #pragma unroll
      for (int mt = 0; mt < 2; mt++){
        const short8* ap = (const short8*)(s_q + (mt*16 + l15)*72);
        #pragma unroll
        for (int k0l = 0; k0l < 2; k0l++){
          const short8 a = ap[k0l*4 + quad];
          const short8 b = *(const short8*)(Bp + ((size_t)(nt*12 + 2*h + k0l)*64 + lane)*8);
          accp[tt][mt] = mfma16(a, b, accp[tt][mt]);
        }
      }
    }
    __syncthreads();   // protect s_q/s_k/s_vT before next head's QKV writes
  }

  // ---- epilogue: +bias +resid, pool over 32 toks, BN, gelu, +ccof*center
  const float fmm  = scal(p_ifmm);
  const float ccof = scal(p_ccof);
  const int cr = cidx[g];
  const int ctok = (cr >> 9)*513 + 1 + (cr & 511);
  #pragma unroll
  for (int tt = 0; tt < 3; tt++){
    const int n = (w*3 + tt)*16 + l15;
    const float bb = b2f(bp1[n]);
    float mx = -3e30f, sm = 0.f;
    #pragma unroll
    for (int mt = 0; mt < 2; mt++){
      #pragma unroll
      for (int r = 0; r < 4; r++){
        const int tok = mt*16 + quad*4 + r;
        const float v = accp[tt][mt][r] + bb + xres[(size_t)s_tok[tok]*384 + n];
        mx = fmaxf(mx, v); sm += v;
      }
    }
    mx = fmaxf(mx, __shfl_xor(mx, 16)); sm += __shfl_xor(sm, 16);
    mx = fmaxf(mx, __shfl_xor(mx, 32)); sm += __shfl_xor(sm, 32);
    if (quad == 0){
      const float lc = (fmm != 0.f) ? (mx + sm*(1.f/32.f)) : mx;
      const float nr = (lc - b2f(bnm[n])) * rsqrtf(b2f(bnv[n]) + 1e-5f) * b2f(bng[n]) + b2f(bnb[n]);
      vis[(size_t)g*384 + n] = geluf(nr) + ccof * xres[(size_t)ctok*384 + n];
    }
  }
}

// ---------------------------------------------------------------------------
// Inverse-distance interpolation: xt[b,n,:] += pro_cof * sum_s w[n,s] vis[b,s,:].
// ---------------------------------------------------------------------------
__global__ __launch_bounds__(256) void interp_kernel(const bf16* __restrict__ c1,
    const bf16* __restrict__ c2, const float* __restrict__ vis,
    const int* __restrict__ p_pcof, float* __restrict__ xres)
{
  __shared__ float s_w[8][128];
  __shared__ float s_red[2];
  const int b = blockIdx.y;
  const int n0 = blockIdx.x * 8;
  const int t = threadIdx.x;
  for (int ni = 0; ni < 8; ni++){
    const int n = n0 + ni;
    float wv = 0.f;
    if (t < 128){
      float d2 = 0.f;
      #pragma unroll
      for (int k = 0; k < 3; k++){
        const float a = b2f(c1[((size_t)b*512 + n)*3 + k]);
        const float c = b2f(c2[((size_t)b*128 + t)*3 + k]);
        const float df = a - c; d2 += df*df;
      }
      wv = 1.f/(d2 + 1e-8f);
    }
    float rsum = wv;
    #pragma unroll
    for (int mm = 32; mm; mm >>= 1) rsum += __shfl_xor(rsum, mm);
    if (((t & 63) == 0) && t < 128) s_red[t >> 6] = rsum;
    __syncthreads();
    const float tot = s_red[0] + s_red[1];
    if (t < 128) s_w[ni][t] = wv / tot;
    __syncthreads();
  }
  float acc1[8], acc2[8];
  #pragma unroll
  for (int ni = 0; ni < 8; ni++){ acc1[ni] = 0.f; acc2[ni] = 0.f; }
  for (int s = 0; s < 128; s++){
    const float* vp = vis + ((size_t)b*128 + s)*384;
    const float v1 = vp[t];
    const float v2 = (t < 128) ? vp[t + 256] : 0.f;
    #pragma unroll
    for (int ni = 0; ni < 8; ni++){
      const float wn = s_w[ni][s];
      acc1[ni] = fmaf(wn, v1, acc1[ni]);
      acc2[ni] = fmaf(wn, v2, acc2[ni]);
    }
  }
  const float pc = scal(p_pcof);
  #pragma unroll
  for (int ni = 0; ni < 8; ni++){
    const int tok = b*513 + 1 + n0 + ni;
    xres[(size_t)tok*384 + t] += pc*acc1[ni];
    if (t < 128) xres[(size_t)tok*384 + t + 256] += pc*acc2[ni];
  }
}

// ---------------------------------------------------------------------------
extern "C" void kernel_launch(void* const* d_in, const int* in_sizes, int n_in,
                              void* d_out, int out_size, void* d_ws, size_t ws_size,
                              hipStream_t stream)
{
  (void)n_in; (void)out_size; (void)ws_size;
  const int*  idx   = (const int*)d_in[35];
  const int*  cidx  = (const int*)d_in[36];
  // d_in[37] = group_size (fixed 32)
  const int*  ifmm  = (const int*)d_in[38];
  const int*  pcof  = (const int*)d_in[39];
  const int*  ccof  = (const int*)d_in[40];

  size_t off = 0;
  auto alloc = [&](size_t bytes) -> void* {
    void* p = (char*)d_ws + off; off += (bytes + 255) & ~(size_t)255; return p;
  };
  int*   flag = (int*)  alloc(sizeof(int));
  float* xres = (float*)alloc((size_t)TOK*384*4);
  bf16*  slab = (bf16*) alloc((size_t)TOK*1536*2);
  bf16*  xn   = (bf16*) alloc((size_t)TOK*384*2);
  float* pq   = (float*)alloc((size_t)10*1152*4);
  bf16*  Bq   = (bf16*) alloc((size_t)72*12*64*8*2);   // shuffled a1_Wqkv
  bf16*  Bp   = (bf16*) alloc((size_t)24*12*64*8*2);   // shuffled a1_Wproj

  bf16*  qkvb = slab;
  bf16*  x_c  = slab + (size_t)TOK*1152;   // canonical x overlays future-h1 tail
  bf16*  h1   = slab;
  float* visb = (float*)slab;
  bf16*  ao   = xn;
  bf16*  hbuf = xn;

  // canonical bf16 copies of all float inputs (skip [3]=neighborhood, ints)
  const int conv_ids[34] = {0,1,2,4,5,6,7,8,9,10,11,12,13,14,15,16,17,
                            18,19,20,21,22,23,24,25,26,27,28,29,30,31,32,33,34};
  ConvArgs ca;
  bf16* canon[41];
  int maxn = 1;
  for (int k = 0; k < 34; k++){
    const int i = conv_ids[k];
    const int n = in_sizes[i];
    bf16* dst = (i == 0) ? x_c : (bf16*)alloc((size_t)n*2);
    ca.src[k] = d_in[i]; ca.dst[k] = dst; ca.n[k] = n;
    canon[i] = dst;
    if (n > maxn) maxn = n;
  }
  // 0a. detect input dtype (fp32 vs bf16)
  detect_kernel<<<dim3(1), dim3(256), 0, stream>>>((const unsigned*)d_in[0], flag);
  // 0b. canonicalize
  {
    int gx = (maxn + 256*64 - 1) / (256*64); if (gx > 64) gx = 64; if (gx < 1) gx = 1;
    convert_many<<<dim3(gx, 34), dim3(256), 0, stream>>>(flag, ca);
  }

  const bf16 *x_in = canon[0], *c1 = canon[1], *c2 = canon[2], *pe = canon[4],
             *ln1g = canon[5], *ln1b = canon[6], *Wqkv = canon[7], *Wproj = canon[8],
             *bproj = canon[9], *gate = canon[10], *ln2g = canon[11], *ln2b = canon[12],
             *W1 = canon[13], *b1 = canon[14], *W2 = canon[15], *b2v = canon[16],
             *adW = canon[17], *adb = canon[18], *adU = canon[19], *adub = canon[20],
             *adg = canon[21], *bng = canon[22], *bnb = canon[23], *bnm = canon[24],
             *bnv = canon[25], *ln3g = canon[26], *ln3b = canon[27], *a1W = canon[28],
             *a1P = canon[29], *a1pb = canon[30], *d1W = canon[31], *d1b = canon[32],
             *u1W = canon[33], *u1b = canon[34];

  // 0c. shuffle local-branch weights into MFMA B-frag order
  shuffle_b<<<dim3(216), dim3(256), 0, stream>>>(a1W, Bq, 1152, 12, 72);
  shuffle_b<<<dim3(72),  dim3(256), 0, stream>>>(a1P, Bp, 384, 12, 24);

  // 1. LN1
  ln_kernel<true><<<dim3((TOK*64)/256), dim3(256), 0, stream>>>((const void*)x_in, ln1g, ln1b, xn, TOK);
  // 2. qkv = xn @ Wqkv
  gemm_kernel<1><<<dim3(18,129), dim3(256), 0, stream>>>(xn, Wqkv, nullptr, nullptr, qkvb, TOK, 1152, 384);
  // 2b. prompt qkv
  pqkv_kernel<<<dim3(18), dim3(256), 0, stream>>>(pe, Wqkv, pq);
  // 3. attention (+ prompt cross-attn) -> ao
  attn_kernel<<<dim3(17,192), dim3(256), 0, stream>>>(qkvb, pq, gate, ao);
  // 4. xres = x + ao @ Wproj + bproj
  gemm_kernel<3><<<dim3(6,129), dim3(256), 0, stream>>>(ao, Wproj, bproj, x_in, xres, TOK, 384, 384);
  // 5. LN2
  ln_kernel<false><<<dim3((TOK*64)/256), dim3(256), 0, stream>>>((const void*)xres, ln2g, ln2b, xn, TOK);
  // 6. h1 = gelu(xn @ W1 + b1)
  gemm_kernel<2><<<dim3(24,129), dim3(256), 0, stream>>>(xn, W1, b1, nullptr, h1, TOK, 1536, 384);
  // 7. h = h1 @ W2 + b2
  gemm_kernel<0><<<dim3(6,129), dim3(256), 0, stream>>>(h1, W2, b2v, nullptr, hbuf, TOK, 384, 1536);
  // 8. adapter mid
  adapter_mid_kernel<<<dim3(TOK), dim3(256), 0, stream>>>(hbuf, adW, adb, adU, adub, adg, xres);
  // 9. fused local branch (MFMA) -> vis
  local_kernel<<<dim3(4096), dim3(512), 0, stream>>>(xres, idx, cidx, ln3g, ln3b, Bq, Bp, a1pb,
                                                     bng, bnb, bnm, bnv, ifmm, ccof, visb);
  // 10. interp
  interp_kernel<<<dim3(64,32), dim3(256), 0, stream>>>(c1, c2, visb, pcof, xres);
  // 11. final adapter -> d_out (dtype per flag)
  adapter_final_kernel<<<dim3(TOK), dim3(256), 0, stream>>>(xres, d1W, d1b, u1W, u1b, flag, d_out);
}

// Round 5
// 1700.988 us; speedup vs baseline: 4.1907x; 1.7391x over previous
//
#include <hip/hip_runtime.h>
#include <hip/hip_bf16.h>
#include <cstdint>
#include <cstddef>

// Problem constants: B=32, G=512, S=128, GS=32, P=10, C=384, H=6, D=64,
// HID=1536, RED=16, tokens per batch = 513.
typedef __hip_bfloat16 bf16;
constexpr int TOK = 32 * 513;   // 16416 rows in the residual stream

typedef __attribute__((ext_vector_type(8))) short short8;
typedef __attribute__((ext_vector_type(4))) float f32x4;

__device__ __forceinline__ float bflo(unsigned u){ return __uint_as_float(u << 16); }
__device__ __forceinline__ float bfhi(unsigned u){ return __uint_as_float(u & 0xffff0000u); }
__device__ __forceinline__ float b2f(bf16 x){ return __bfloat162float(x); }
__device__ __forceinline__ bf16  f2b(float x){ return __float2bfloat16(x); }
__device__ __forceinline__ float geluf(float x){ return 0.5f*x*(1.0f + erff(x*0.70710678118654752f)); }
__device__ __forceinline__ void unp8(uint4 u, float* f){
  f[0]=bflo(u.x); f[1]=bfhi(u.x); f[2]=bflo(u.y); f[3]=bfhi(u.y);
  f[4]=bflo(u.z); f[5]=bfhi(u.z); f[6]=bflo(u.w); f[7]=bfhi(u.w);
}
// Scalar decode robust to int32-vs-float32 materialization of Python scalars.
__device__ __forceinline__ float scal(const int* p){
  const int i = *p;
  if (i > -1000000 && i < 1000000) return (float)i;
  return __int_as_float(i);
}
__device__ __forceinline__ f32x4 mfma16(short8 a, short8 b, f32x4 c){
  return __builtin_amdgcn_mfma_f32_16x16x32_bf16(a, b, c, 0, 0, 0);
}

// ---------------------------------------------------------------------------
// Dtype detection: if any 16-bit half of x's first 2048 words, viewed as bf16,
// is NaN or |v|>1e6 => inputs are fp32 (flag=1). bf16 inputs (|x|<~6) => 0.
// ---------------------------------------------------------------------------
__global__ __launch_bounds__(256) void detect_kernel(const unsigned* __restrict__ x,
                                                     int* __restrict__ flag)
{
  const int t = threadIdx.x;
  bool bad = false;
  for (int i = t; i < 2048; i += 256){
    const unsigned u = x[i];
    const float a = fabsf(bflo(u)), b = fabsf(bfhi(u));
    if (!(a < 1e6f) || !(b < 1e6f)) bad = true;   // NaN fails the compare
  }
  __shared__ int s;
  if (t == 0) s = 0;
  __syncthreads();
  const unsigned long long m = __ballot(bad);
  if (m != 0ull && (t & 63) == 0) atomicOr(&s, 1);
  __syncthreads();
  if (t == 0) *flag = s;
}

// ---------------------------------------------------------------------------
// Canonicalize all float inputs to bf16 (copy if already bf16).
// ---------------------------------------------------------------------------
struct ConvArgs {
  const void* src[34];
  bf16*       dst[34];
  int         n[34];
};
__global__ __launch_bounds__(256) void convert_many(const int* __restrict__ flag, ConvArgs a)
{
  const int ii = blockIdx.y;
  const bool isf = (*flag != 0);
  const int n = a.n[ii];
  const void* s = a.src[ii];
  bf16* d = a.dst[ii];
  for (int i = blockIdx.x*256 + threadIdx.x; i < n; i += gridDim.x*256){
    d[i] = isf ? f2b(((const float*)s)[i]) : ((const bf16*)s)[i];
  }
}

// ---------------------------------------------------------------------------
// Shuffle weight W[K x N] (row-major) into MFMA B-fragment order.
// ---------------------------------------------------------------------------
__global__ __launch_bounds__(256) void shuffle_b(const bf16* __restrict__ W,
    bf16* __restrict__ out, int N, int KT, int NT)
{
  const int id = blockIdx.x*256 + threadIdx.x;
  if (id >= NT*KT*64) return;
  const int l  = id & 63;
  const int k0 = (id >> 6) % KT;
  const int n0 = (id >> 6) / KT;
  bf16 tmp[8];
  #pragma unroll
  for (int j = 0; j < 8; j++)
    tmp[j] = W[(size_t)(k0*32 + (l>>4)*8 + j)*N + n0*16 + (l&15)];
  *(uint4*)(out + (size_t)id*8) = *(const uint4*)tmp;
}

// ---------------------------------------------------------------------------
// LayerNorm: one wave per row of 384. Output bf16.
// ---------------------------------------------------------------------------
template<bool SRC_BF16>
__global__ __launch_bounds__(256) void ln_kernel(const void* __restrict__ src,
    const bf16* __restrict__ g, const bf16* __restrict__ b,
    bf16* __restrict__ out, int rows)
{
  const int wave = (blockIdx.x * blockDim.x + threadIdx.x) >> 6;
  const int lane = threadIdx.x & 63;
  if (wave >= rows) return;
  float v[6]; float s = 0.f, s2 = 0.f;
  #pragma unroll
  for (int i = 0; i < 6; i++){
    const int c = lane + 64*i;
    float x;
    if (SRC_BF16) x = b2f(((const bf16*)src)[(size_t)wave*384 + c]);
    else          x = ((const float*)src)[(size_t)wave*384 + c];
    v[i] = x; s += x; s2 += x*x;
  }
  #pragma unroll
  for (int mm = 32; mm; mm >>= 1){ s += __shfl_xor(s, mm); s2 += __shfl_xor(s2, mm); }
  const float mean = s * (1.f/384.f);
  const float rs = rsqrtf(s2 * (1.f/384.f) - mean*mean + 1e-5f);
  #pragma unroll
  for (int i = 0; i < 6; i++){
    const int c = lane + 64*i;
    out[(size_t)wave*384 + c] = f2b((v[i]-mean)*rs*b2f(g[c]) + b2f(b[c]));
  }
}

// ---------------------------------------------------------------------------
// Tiled GEMM (fp32 VALU): out[M,N] = A[M,K] @ W[K,N] (+bias, epilogue). A bf16.
// EPI: 0 = bf16 out, +bias; 1 = bf16 out; 2 = bf16 out gelu(+bias);
//      3 = f32 out, +bias +bf16resid
// ---------------------------------------------------------------------------
template<int EPI>
__global__ __launch_bounds__(256) void gemm_kernel(
    const bf16* __restrict__ A, const bf16* __restrict__ W,
    const bf16* __restrict__ bias, const bf16* __restrict__ resid,
    void* __restrict__ outv, int M, int N, int K)
{
  __shared__ float As[16][129];   // [k][m], +1 pad
  __shared__ float Ws[16][64];    // [k][n]
  const int t  = threadIdx.x;
  const int m0 = blockIdx.y * 128;
  const int n0 = blockIdx.x * 64;
  const int tx = t & 15, ty = t >> 4;
  float acc[8][4];
  #pragma unroll
  for (int i = 0; i < 8; i++){
    #pragma unroll
    for (int j = 0; j < 4; j++) acc[i][j] = 0.f;
  }
  const int ar  = t >> 1;
  const int kc  = (t & 1) * 8;
  const int wkr = t >> 4;
  const int wnc = (t & 15) * 4;

  for (int k0 = 0; k0 < K; k0 += 16){
    float av[8];
    const int gm = m0 + ar;
    if (gm < M){
      uint4 u = *(const uint4*)(A + (size_t)gm*K + k0 + kc);
      unp8(u, av);
    } else {
      #pragma unroll
      for (int i = 0; i < 8; i++) av[i] = 0.f;
    }
    #pragma unroll
    for (int i = 0; i < 8; i++) As[kc+i][ar] = av[i];
    {
      uint2 u = *(const uint2*)(W + (size_t)(k0+wkr)*N + n0 + wnc);
      Ws[wkr][wnc+0]=bflo(u.x); Ws[wkr][wnc+1]=bfhi(u.x);
      Ws[wkr][wnc+2]=bflo(u.y); Ws[wkr][wnc+3]=bfhi(u.y);
    }
    __syncthreads();
    #pragma unroll
    for (int kk = 0; kk < 16; kk++){
      float a[8];
      #pragma unroll
      for (int i = 0; i < 8; i++) a[i] = As[kk][ty*8+i];
      float4 wb = *(const float4*)&Ws[kk][tx*4];
      #pragma unroll
      for (int i = 0; i < 8; i++){
        acc[i][0] = fmaf(a[i], wb.x, acc[i][0]);
        acc[i][1] = fmaf(a[i], wb.y, acc[i][1]);
        acc[i][2] = fmaf(a[i], wb.z, acc[i][2]);
        acc[i][3] = fmaf(a[i], wb.w, acc[i][3]);
      }
    }
    __syncthreads();
  }
  const int gn0 = n0 + tx*4;
  #pragma unroll
  for (int i = 0; i < 8; i++){
    const int gm = m0 + ty*8 + i;
    if (gm < M){
      #pragma unroll
      for (int j = 0; j < 4; j++){
        float v = acc[i][j];
        const int gn = gn0 + j;
        const size_t o = (size_t)gm*N + gn;
        if (EPI == 0){ v += b2f(bias[gn]); ((bf16*)outv)[o] = f2b(v); }
        else if (EPI == 1){ ((bf16*)outv)[o] = f2b(v); }
        else if (EPI == 2){ v += b2f(bias[gn]); ((bf16*)outv)[o] = f2b(geluf(v)); }
        else { v += b2f(bias[gn]) + b2f(resid[o]); ((float*)outv)[o] = v; }
      }
    }
  }
}

// ---------------------------------------------------------------------------
// Prompt QKV: (10 x 384) @ (384 x 1152) -> f32 (prompt used WITHOUT LN).
// ---------------------------------------------------------------------------
__global__ __launch_bounds__(256) void pqkv_kernel(const bf16* __restrict__ pe,
    const bf16* __restrict__ Wqkv, float* __restrict__ pq)
{
  const int n  = blockIdx.x*64 + (threadIdx.x & 63);
  const int rg = threadIdx.x >> 6;
  for (int r = rg; r < 10; r += 4){
    float s0 = 0.f, s1 = 0.f;
    for (int c = 0; c < 384; c += 2){
      s0 = fmaf(b2f(pe[(size_t)r*384+c]),   b2f(Wqkv[(size_t)c*1152 + n]),     s0);
      s1 = fmaf(b2f(pe[(size_t)r*384+c+1]), b2f(Wqkv[(size_t)(c+1)*1152 + n]), s1);
    }
    pq[(size_t)r*1152 + n] = s0 + s1;
  }
}

// ---------------------------------------------------------------------------
// Main attention (MFMA flash) + prompt cross-attention fused.
// grid = (9 q-chunks of 64 rows, 192 b*h). 256 threads = 4 waves x 16-row tile.
// MFMA layouts (verified by passing local_kernel): A[m=l15][k=quad*8+j],
// B[k=quad*8+j][n=l15], D[row=quad*4+r][col=l15].
// ---------------------------------------------------------------------------
__global__ __launch_bounds__(256) void attn_kernel(
    const bf16* __restrict__ qkv, const float* __restrict__ pq,
    const bf16* __restrict__ gate, bf16* __restrict__ ao)
{
  __shared__ __align__(16) bf16 s_q[64*72];     // Q rows, stride 72
  __shared__ __align__(16) bf16 s_k[64*72];     // K-tile rows (by key)
  __shared__ __align__(16) bf16 s_vT[64*72];    // V transposed [d][key]
  __shared__ __align__(16) bf16 s_p[4*16*40];   // per-wave P (16 rows x 40)
  __shared__ __align__(16) bf16 s_pk[16*72];    // prompt K (rows >=10 zero)
  __shared__ __align__(16) bf16 s_pvT[64*40];   // prompt V^T [d][key<32]
  const int bh = blockIdx.y;
  const int b = bh / 6, h = bh % 6;
  const int q0 = blockIdx.x * 64;
  const int t = threadIdx.x, lane = t & 63, w = t >> 6;
  const int l15 = lane & 15, quad = lane >> 4;

  { // stage Q: 64 rows x 64 d
    const int row = t >> 2, dc = (t & 3) * 16;
    const int tok = q0 + row;
    uint4 u0 = {0,0,0,0}, u1 = {0,0,0,0};
    if (tok < 513){
      const bf16* p = qkv + (size_t)(b*513 + tok)*1152 + h*64 + dc;
      u0 = *(const uint4*)p; u1 = *(const uint4*)(p + 8);
    }
    *(uint4*)(s_q + row*72 + dc)     = u0;
    *(uint4*)(s_q + row*72 + dc + 8) = u1;
  }
  { // stage prompt K (16x64, rows>=10 zero)
    const int j = t >> 4, dc = (t & 15) * 4;
    float f[4] = {0.f,0.f,0.f,0.f};
    if (j < 10){
      const float* pk = pq + (size_t)j*1152 + 384 + h*64 + dc;
      f[0]=pk[0]; f[1]=pk[1]; f[2]=pk[2]; f[3]=pk[3];
    }
    bf16 tmp[4] = {f2b(f[0]),f2b(f[1]),f2b(f[2]),f2b(f[3])};
    *(uint2*)(s_pk + j*72 + dc) = *(const uint2*)tmp;
  }
  { // stage prompt V^T [d][key], keys >= 10 zero (padded to 32)
    const int d = t & 63, kg = t >> 6;
    #pragma unroll
    for (int kk = 0; kk < 8; kk++){
      const int key = kg*8 + kk;
      bf16 v = f2b(0.f);
      if (key < 10) v = f2b(pq[(size_t)key*1152 + 768 + h*64 + d]);
      s_pvT[d*40 + key] = v;
    }
  }

  float m_i[4], l_i[4];
  f32x4 oacc[4];
  #pragma unroll
  for (int r = 0; r < 4; r++){ m_i[r] = -30000.f; l_i[r] = 0.f; }
  #pragma unroll
  for (int nt = 0; nt < 4; nt++) oacc[nt] = f32x4{0.f,0.f,0.f,0.f};
  bf16* myp = s_p + w*16*40;
  const short8* aq = (const short8*)(s_q + (w*16 + l15)*72);

  for (int kt = 0; kt < 9; kt++){
    const int kb = kt*64;
    __syncthreads();
    { // stage K/V tile: each thread 2 keys x 8 d; V interleaved into s_vT
      const int kp = t & 31, dg = t >> 5;
      const int key0 = kb + 2*kp;
      uint4 k0v = {0,0,0,0}, k1v = {0,0,0,0}, v0 = {0,0,0,0}, v1 = {0,0,0,0};
      if (key0 < 513){
        const bf16* base = qkv + (size_t)(b*513 + key0)*1152 + h*64 + dg*8;
        k0v = *(const uint4*)(base + 384);
        v0  = *(const uint4*)(base + 768);
      }
      if (key0 + 1 < 513){
        const bf16* base = qkv + (size_t)(b*513 + key0 + 1)*1152 + h*64 + dg*8;
        k1v = *(const uint4*)(base + 384);
        v1  = *(const uint4*)(base + 768);
      }
      *(uint4*)(s_k + (2*kp)*72   + dg*8) = k0v;
      *(uint4*)(s_k + (2*kp+1)*72 + dg*8) = k1v;
      const unsigned short* a0 = (const unsigned short*)&v0;
      const unsigned short* a1 = (const unsigned short*)&v1;
      unsigned* vt = (unsigned*)s_vT;
      #pragma unroll
      for (int j = 0; j < 8; j++)
        vt[(dg*8 + j)*36 + kp] = (unsigned)a0[j] | ((unsigned)a1[j] << 16);
    }
    __syncthreads();

    // S = Q K^T * scale (C-layout registers), mask invalid keys
    f32x4 sreg[4];
    #pragma unroll
    for (int nt = 0; nt < 4; nt++){
      f32x4 acc = f32x4{0.f,0.f,0.f,0.f};
      const short8* bk = (const short8*)(s_k + (nt*16 + l15)*72);
      acc = mfma16(aq[quad],     bk[quad],     acc);
      acc = mfma16(aq[4 + quad], bk[4 + quad], acc);
      const bool kvalid = (kb + nt*16 + l15) < 513;
      #pragma unroll
      for (int r = 0; r < 4; r++)
        sreg[nt][r] = kvalid ? acc[r]*0.125f : -30000.f;
    }
    // online softmax (row group = 16 lanes sharing quad)
    float alpha[4];
    #pragma unroll
    for (int r = 0; r < 4; r++){
      float mx = fmaxf(fmaxf(sreg[0][r], sreg[1][r]), fmaxf(sreg[2][r], sreg[3][r]));
      #pragma unroll
      for (int mm = 8; mm; mm >>= 1) mx = fmaxf(mx, __shfl_xor(mx, mm));
      const float mn = fmaxf(m_i[r], mx);
      alpha[r] = __expf(m_i[r] - mn);
      m_i[r] = mn;
      float ps = 0.f;
      #pragma unroll
      for (int nt = 0; nt < 4; nt++){
        const float p = __expf(sreg[nt][r] - mn);
        sreg[nt][r] = p; ps += p;
      }
      #pragma unroll
      for (int mm = 8; mm; mm >>= 1) ps += __shfl_xor(ps, mm);
      l_i[r] = l_i[r]*alpha[r] + ps;
    }
    // write P (bf16) to per-wave buffer; rescale O
    #pragma unroll
    for (int nt = 0; nt < 4; nt++){
      #pragma unroll
      for (int r = 0; r < 4; r++)
        myp[(quad*4 + r)*40 + nt*16 + l15] = f2b(sreg[nt][r]);
    }
    #pragma unroll
    for (int nt = 0; nt < 4; nt++){
      #pragma unroll
      for (int r = 0; r < 4; r++) oacc[nt][r] *= alpha[r];
    }
    // O += P V
    const short8* ap = (const short8*)(myp + l15*40);
    #pragma unroll
    for (int nt = 0; nt < 4; nt++){
      const short8* bv = (const short8*)(s_vT + (nt*16 + l15)*72);
      oacc[nt] = mfma16(ap[quad],     bv[quad],     oacc[nt]);
      oacc[nt] = mfma16(ap[4 + quad], bv[4 + quad], oacc[nt]);
    }
  }

  // ---- prompt cross-attention (keys padded to 16/32) ----
  f32x4 sp;
  {
    f32x4 acc = f32x4{0.f,0.f,0.f,0.f};
    const short8* bp = (const short8*)(s_pk + l15*72);
    acc = mfma16(aq[quad],     bp[quad],     acc);
    acc = mfma16(aq[4 + quad], bp[4 + quad], acc);
    #pragma unroll
    for (int r = 0; r < 4; r++)
      sp[r] = (l15 < 10) ? acc[r]*0.125f : -30000.f;
  }
  float psr[4];
  #pragma unroll
  for (int r = 0; r < 4; r++){
    float mx = sp[r];
    #pragma unroll
    for (int mm = 8; mm; mm >>= 1) mx = fmaxf(mx, __shfl_xor(mx, mm));
    const float p = __expf(sp[r] - mx);
    float ps = p;
    #pragma unroll
    for (int mm = 8; mm; mm >>= 1) ps += __shfl_xor(ps, mm);
    psr[r] = ps;
    myp[(quad*4 + r)*40 + l15]      = f2b(p);
    myp[(quad*4 + r)*40 + 16 + l15] = f2b(0.f);
  }
  f32x4 pva[4];
  {
    const short8* ap = (const short8*)(myp + l15*40);
    #pragma unroll
    for (int nt = 0; nt < 4; nt++){
      const short8* bv = (const short8*)(s_pvT + (nt*16 + l15)*40);
      pva[nt] = mfma16(ap[quad], bv[quad], f32x4{0.f,0.f,0.f,0.f});
    }
  }

  // ---- store: ao = O/l + gate * PV/ps
  const float gh = b2f(gate[h]);
  #pragma unroll
  for (int r = 0; r < 4; r++){
    const int tok = q0 + w*16 + quad*4 + r;
    if (tok < 513){
      const float invl = 1.f/l_i[r];
      const float gps  = gh/psr[r];
      #pragma unroll
      for (int nt = 0; nt < 4; nt++){
        const float val = oacc[nt][r]*invl + pva[nt][r]*gps;
        ao[(size_t)(b*513 + tok)*384 + h*64 + nt*16 + l15] = f2b(val);
      }
    }
  }
}

// ---------------------------------------------------------------------------
// Adapter (mid): xres = ad_gate*(h + gelu(h@Wd+bd)@Wu + bu) + xres. 1 block/row.
// ---------------------------------------------------------------------------
__global__ __launch_bounds__(256) void adapter_mid_kernel(const bf16* __restrict__ h,
    const bf16* __restrict__ Wd, const bf16* __restrict__ bd,
    const bf16* __restrict__ Wu, const bf16* __restrict__ bu,
    const bf16* __restrict__ p_gate, float* __restrict__ xres)
{
  __shared__ float s_h[384];
  __shared__ float s_part[16][17];
  __shared__ float s_y[16];
  const size_t row = blockIdx.x;
  const int t = threadIdx.x;
  const bf16* hp = h + row*384;
  for (int c = t; c < 384; c += 256) s_h[c] = b2f(hp[c]);
  __syncthreads();
  const int o = t & 15, p = t >> 4;
  float part0 = 0.f, part1 = 0.f;
  for (int c = p; c < 384; c += 32){
    part0 = fmaf(s_h[c],    b2f(Wd[(size_t)c*16 + o]),      part0);
    part1 = fmaf(s_h[c+16], b2f(Wd[(size_t)(c+16)*16 + o]), part1);
  }
  s_part[o][p] = part0 + part1;
  __syncthreads();
  if (t < 16){
    float sum = 0.f;
    #pragma unroll
    for (int pp = 0; pp < 16; pp++) sum += s_part[t][pp];
    s_y[t] = geluf(sum + b2f(bd[t]));
  }
  __syncthreads();
  const float g = b2f(p_gate[0]);
  for (int c = t; c < 384; c += 256){
    float up = 0.f;
    #pragma unroll
    for (int o2 = 0; o2 < 16; o2++) up = fmaf(s_y[o2], b2f(Wu[(size_t)o2*384 + c]), up);
    const float had = s_h[c] + up + b2f(bu[c]);
    xres[row*384 + c] = g*had + xres[row*384 + c];
  }
}

// ---------------------------------------------------------------------------
// Final adapter: out = xres + gelu(xres@Wd+bd)@Wu + bu. Output dtype per flag.
// ---------------------------------------------------------------------------
__global__ __launch_bounds__(256) void adapter_final_kernel(const float* __restrict__ xr,
    const bf16* __restrict__ Wd, const bf16* __restrict__ bd,
    const bf16* __restrict__ Wu, const bf16* __restrict__ bu,
    const int* __restrict__ flag, void* __restrict__ out)
{
  __shared__ float s_h[384];
  __shared__ float s_part[16][17];
  __shared__ float s_y[16];
  const size_t row = blockIdx.x;
  const int t = threadIdx.x;
  const float* hp = xr + row*384;
  for (int c = t; c < 384; c += 256) s_h[c] = hp[c];
  __syncthreads();
  const int o = t & 15, p = t >> 4;
  float part0 = 0.f, part1 = 0.f;
  for (int c = p; c < 384; c += 32){
    part0 = fmaf(s_h[c],    b2f(Wd[(size_t)c*16 + o]),      part0);
    part1 = fmaf(s_h[c+16], b2f(Wd[(size_t)(c+16)*16 + o]), part1);
  }
  s_part[o][p] = part0 + part1;
  __syncthreads();
  if (t < 16){
    float sum = 0.f;
    #pragma unroll
    for (int pp = 0; pp < 16; pp++) sum += s_part[t][pp];
    s_y[t] = geluf(sum + b2f(bd[t]));
  }
  __syncthreads();
  const bool isf = (*flag != 0);
  for (int c = t; c < 384; c += 256){
    float up = 0.f;
    #pragma unroll
    for (int o2 = 0; o2 < 16; o2++) up = fmaf(s_y[o2], b2f(Wu[(size_t)o2*384 + c]), up);
    const float v = s_h[c] + up + b2f(bu[c]);
    if (isf) ((float*)out)[row*384 + c] = v;
    else     ((bf16*)out)[row*384 + c] = f2b(v);
  }
}

// ---------------------------------------------------------------------------
// Fused local branch (MFMA): one block (512 thr, 8 waves) per group.
// ---------------------------------------------------------------------------
__global__ __launch_bounds__(512) void local_kernel(
    const float* __restrict__ xres, const int* __restrict__ idx, const int* __restrict__ cidx,
    const bf16* __restrict__ ln3g, const bf16* __restrict__ ln3b,
    const bf16* __restrict__ Bq, const bf16* __restrict__ Bp, const bf16* __restrict__ bp1,
    const bf16* __restrict__ bng, const bf16* __restrict__ bnb,
    const bf16* __restrict__ bnm, const bf16* __restrict__ bnv,
    const int* __restrict__ p_ifmm, const int* __restrict__ p_ccof,
    float* __restrict__ vis)
{
  __shared__ __align__(16) bf16  s_xln[32*392];
  __shared__ __align__(16) bf16  s_q[32*72];
  __shared__ __align__(16) bf16  s_k[32*72];
  __shared__ __align__(16) bf16  s_vT[64*40];
  __shared__ __align__(16) float s_S[32*33];
  __shared__ __align__(16) bf16  s_p[32*40];
  __shared__ int s_tok[32];

  const int g = blockIdx.x;
  const int t = threadIdx.x, lane = t & 63, w = t >> 6;
  const int l15 = lane & 15, quad = lane >> 4;

  if (t < 32){
    const int r = idx[g*32 + t];
    s_tok[t] = (r >> 9)*513 + 1 + (r & 511);
  }
  __syncthreads();

  #pragma unroll
  for (int i = 0; i < 4; i++){
    const int r = w*4 + i;
    const float* xp = xres + (size_t)s_tok[r]*384;
    float vv[6]; float s = 0.f, s2 = 0.f;
    #pragma unroll
    for (int c6 = 0; c6 < 6; c6++){ float x = xp[lane + 64*c6]; vv[c6] = x; s += x; s2 += x*x; }
    #pragma unroll
    for (int mm = 32; mm; mm >>= 1){ s += __shfl_xor(s, mm); s2 += __shfl_xor(s2, mm); }
    const float mean = s*(1.f/384.f);
    const float rs = rsqrtf(s2*(1.f/384.f) - mean*mean + 1e-5f);
    #pragma unroll
    for (int c6 = 0; c6 < 6; c6++){
      const int c = lane + 64*c6;
      s_xln[r*392 + c] = f2b((vv[c6]-mean)*rs*b2f(ln3g[c]) + b2f(ln3b[c]));
    }
  }
  __syncthreads();

  f32x4 accp[3][2];
  #pragma unroll
  for (int a = 0; a < 3; a++){
    #pragma unroll
    for (int m = 0; m < 2; m++) accp[a][m] = f32x4{0.f,0.f,0.f,0.f};
  }

  for (int h = 0; h < 6; h++){
    #pragma unroll
    for (int tt = 0; tt < 3; tt++){
      const int id = w + tt*8;
      const int mt = id / 12, j = id % 12;
      const int grp = j >> 2, jc = j & 3;
      const int gnt = grp*24 + h*4 + jc;
      f32x4 acc = f32x4{0.f,0.f,0.f,0.f};
      const short8* ap = (const short8*)(s_xln + (mt*16 + l15)*392);
      const bf16* bptr = Bq + ((size_t)(gnt*12)*64 + lane)*8;
      #pragma unroll 4
      for (int k0 = 0; k0 < 12; k0++){
        const short8 a = ap[k0*4 + quad];
        const short8 b = *(const short8*)(bptr + (size_t)k0*64*8);
        acc = mfma16(a, b, acc);
      }
      #pragma unroll
      for (int r = 0; r < 4; r++){
        const int tok = mt*16 + quad*4 + r;
        const bf16 v = f2b(acc[r]);
        if (grp == 0)      s_q[tok*72 + jc*16 + l15] = v;
        else if (grp == 1) s_k[tok*72 + jc*16 + l15] = v;
        else               s_vT[(jc*16 + l15)*40 + tok] = v;
      }
    }
    __syncthreads();

    if (w < 4){
      const int mt = w & 1, nt = w >> 1;
      f32x4 acc = f32x4{0.f,0.f,0.f,0.f};
      const short8* ap = (const short8*)(s_q + (mt*16 + l15)*72);
      const short8* bp = (const short8*)(s_k + (nt*16 + l15)*72);
      #pragma unroll
      for (int k0 = 0; k0 < 2; k0++)
        acc = mfma16(ap[k0*4 + quad], bp[k0*4 + quad], acc);
      #pragma unroll
      for (int r = 0; r < 4; r++)
        s_S[(mt*16 + quad*4 + r)*33 + nt*16 + l15] = acc[r]*0.125f;
    }
    __syncthreads();

    {
      const int row = t >> 4, col = t & 15;
      const float v0 = s_S[row*33 + col], v1 = s_S[row*33 + col + 16];
      float mx = fmaxf(v0, v1);
      #pragma unroll
      for (int mm = 8; mm; mm >>= 1) mx = fmaxf(mx, __shfl_xor(mx, mm));
      const float e0 = __expf(v0 - mx), e1 = __expf(v1 - mx);
      float sm = e0 + e1;
      #pragma unroll
      for (int mm = 8; mm; mm >>= 1) sm += __shfl_xor(sm, mm);
      const float inv = 1.f/sm;
      s_p[row*40 + col]      = f2b(e0*inv);
      s_p[row*40 + col + 16] = f2b(e1*inv);
    }
    __syncthreads();

    {
      const int mt = w & 1, nt = w >> 1;
      const short8 a = *(const short8*)(s_p + (mt*16 + l15)*40 + quad*8);
      const short8 b = *(const short8*)(s_vT + (nt*16 + l15)*40 + quad*8);
      f32x4 acc = mfma16(a, b, f32x4{0.f,0.f,0.f,0.f});
      #pragma unroll
      for (int r = 0; r < 4; r++)
        s_q[(mt*16 + quad*4 + r)*72 + nt*16 + l15] = f2b(acc[r]);
    }
    __syncthreads();

    #pragma unroll
    for (int tt = 0; tt < 3; tt++){
      const int nt = w*3 + tt;
      #pragma unroll
      for (int mt = 0; mt < 2; mt++){
        const short8* ap = (const short8*)(s_q + (mt*16 + l15)*72);
        #pragma unroll
        for (int k0l = 0; k0l < 2; k0l++){
          const short8 a = ap[k0l*4 + quad];
          const short8 b = *(const short8*)(Bp + ((size_t)(nt*12 + 2*h + k0l)*64 + lane)*8);
          accp[tt][mt] = mfma16(a, b, accp[tt][mt]);
        }
      }
    }
    __syncthreads();
  }

  const float fmm  = scal(p_ifmm);
  const float ccof = scal(p_ccof);
  const int cr = cidx[g];
  const int ctok = (cr >> 9)*513 + 1 + (cr & 511);
  #pragma unroll
  for (int tt = 0; tt < 3; tt++){
    const int n = (w*3 + tt)*16 + l15;
    const float bb = b2f(bp1[n]);
    float mx = -3e30f, sm = 0.f;
    #pragma unroll
    for (int mt = 0; mt < 2; mt++){
      #pragma unroll
      for (int r = 0; r < 4; r++){
        const int tok = mt*16 + quad*4 + r;
        const float v = accp[tt][mt][r] + bb + xres[(size_t)s_tok[tok]*384 + n];
        mx = fmaxf(mx, v); sm += v;
      }
    }
    mx = fmaxf(mx, __shfl_xor(mx, 16)); sm += __shfl_xor(sm, 16);
    mx = fmaxf(mx, __shfl_xor(mx, 32)); sm += __shfl_xor(sm, 32);
    if (quad == 0){
      const float lc = (fmm != 0.f) ? (mx + sm*(1.f/32.f)) : mx;
      const float nr = (lc - b2f(bnm[n])) * rsqrtf(b2f(bnv[n]) + 1e-5f) * b2f(bng[n]) + b2f(bnb[n]);
      vis[(size_t)g*384 + n] = geluf(nr) + ccof * xres[(size_t)ctok*384 + n];
    }
  }
}

// ---------------------------------------------------------------------------
// Inverse-distance interpolation: xt[b,n,:] += pro_cof * sum_s w[n,s] vis[b,s,:].
// ---------------------------------------------------------------------------
__global__ __launch_bounds__(256) void interp_kernel(const bf16* __restrict__ c1,
    const bf16* __restrict__ c2, const float* __restrict__ vis,
    const int* __restrict__ p_pcof, float* __restrict__ xres)
{
  __shared__ float s_w[8][128];
  __shared__ float s_red[2];
  const int b = blockIdx.y;
  const int n0 = blockIdx.x * 8;
  const int t = threadIdx.x;
  for (int ni = 0; ni < 8; ni++){
    const int n = n0 + ni;
    float wv = 0.f;
    if (t < 128){
      float d2 = 0.f;
      #pragma unroll
      for (int k = 0; k < 3; k++){
        const float a = b2f(c1[((size_t)b*512 + n)*3 + k]);
        const float c = b2f(c2[((size_t)b*128 + t)*3 + k]);
        const float df = a - c; d2 += df*df;
      }
      wv = 1.f/(d2 + 1e-8f);
    }
    float rsum = wv;
    #pragma unroll
    for (int mm = 32; mm; mm >>= 1) rsum += __shfl_xor(rsum, mm);
    if (((t & 63) == 0) && t < 128) s_red[t >> 6] = rsum;
    __syncthreads();
    const float tot = s_red[0] + s_red[1];
    if (t < 128) s_w[ni][t] = wv / tot;
    __syncthreads();
  }
  float acc1[8], acc2[8];
  #pragma unroll
  for (int ni = 0; ni < 8; ni++){ acc1[ni] = 0.f; acc2[ni] = 0.f; }
  for (int s = 0; s < 128; s++){
    const float* vp = vis + ((size_t)b*128 + s)*384;
    const float v1 = vp[t];
    const float v2 = (t < 128) ? vp[t + 256] : 0.f;
    #pragma unroll
    for (int ni = 0; ni < 8; ni++){
      const float wn = s_w[ni][s];
      acc1[ni] = fmaf(wn, v1, acc1[ni]);
      acc2[ni] = fmaf(wn, v2, acc2[ni]);
    }
  }
  const float pc = scal(p_pcof);
  #pragma unroll
  for (int ni = 0; ni < 8; ni++){
    const int tok = b*513 + 1 + n0 + ni;
    xres[(size_t)tok*384 + t] += pc*acc1[ni];
    if (t < 128) xres[(size_t)tok*384 + t + 256] += pc*acc2[ni];
  }
}

// ---------------------------------------------------------------------------
extern "C" void kernel_launch(void* const* d_in, const int* in_sizes, int n_in,
                              void* d_out, int out_size, void* d_ws, size_t ws_size,
                              hipStream_t stream)
{
  (void)n_in; (void)out_size; (void)ws_size;
  const int*  idx   = (const int*)d_in[35];
  const int*  cidx  = (const int*)d_in[36];
  const int*  ifmm  = (const int*)d_in[38];
  const int*  pcof  = (const int*)d_in[39];
  const int*  ccof  = (const int*)d_in[40];

  size_t off = 0;
  auto alloc = [&](size_t bytes) -> void* {
    void* p = (char*)d_ws + off; off += (bytes + 255) & ~(size_t)255; return p;
  };
  int*   flag = (int*)  alloc(sizeof(int));
  float* xres = (float*)alloc((size_t)TOK*384*4);
  bf16*  slab = (bf16*) alloc((size_t)TOK*1536*2);
  bf16*  xn   = (bf16*) alloc((size_t)TOK*384*2);
  float* pq   = (float*)alloc((size_t)10*1152*4);
  bf16*  Bq   = (bf16*) alloc((size_t)72*12*64*8*2);   // shuffled a1_Wqkv
  bf16*  Bp   = (bf16*) alloc((size_t)24*12*64*8*2);   // shuffled a1_Wproj

  bf16*  qkvb = slab;
  bf16*  x_c  = slab + (size_t)TOK*1152;
  bf16*  h1   = slab;
  float* visb = (float*)slab;
  bf16*  ao   = xn;
  bf16*  hbuf = xn;

  const int conv_ids[34] = {0,1,2,4,5,6,7,8,9,10,11,12,13,14,15,16,17,
                            18,19,20,21,22,23,24,25,26,27,28,29,30,31,32,33,34};
  ConvArgs ca;
  bf16* canon[41];
  int maxn = 1;
  for (int k = 0; k < 34; k++){
    const int i = conv_ids[k];
    const int n = in_sizes[i];
    bf16* dst = (i == 0) ? x_c : (bf16*)alloc((size_t)n*2);
    ca.src[k] = d_in[i]; ca.dst[k] = dst; ca.n[k] = n;
    canon[i] = dst;
    if (n > maxn) maxn = n;
  }
  detect_kernel<<<dim3(1), dim3(256), 0, stream>>>((const unsigned*)d_in[0], flag);
  {
    int gx = (maxn + 256*64 - 1) / (256*64); if (gx > 64) gx = 64; if (gx < 1) gx = 1;
    convert_many<<<dim3(gx, 34), dim3(256), 0, stream>>>(flag, ca);
  }

  const bf16 *x_in = canon[0], *c1 = canon[1], *c2 = canon[2], *pe = canon[4],
             *ln1g = canon[5], *ln1b = canon[6], *Wqkv = canon[7], *Wproj = canon[8],
             *bproj = canon[9], *gate = canon[10], *ln2g = canon[11], *ln2b = canon[12],
             *W1 = canon[13], *b1 = canon[14], *W2 = canon[15], *b2v = canon[16],
             *adW = canon[17], *adb = canon[18], *adU = canon[19], *adub = canon[20],
             *adg = canon[21], *bng = canon[22], *bnb = canon[23], *bnm = canon[24],
             *bnv = canon[25], *ln3g = canon[26], *ln3b = canon[27], *a1W = canon[28],
             *a1P = canon[29], *a1pb = canon[30], *d1W = canon[31], *d1b = canon[32],
             *u1W = canon[33], *u1b = canon[34];

  shuffle_b<<<dim3(216), dim3(256), 0, stream>>>(a1W, Bq, 1152, 12, 72);
  shuffle_b<<<dim3(72),  dim3(256), 0, stream>>>(a1P, Bp, 384, 12, 24);

  // 1. LN1
  ln_kernel<true><<<dim3((TOK*64)/256), dim3(256), 0, stream>>>((const void*)x_in, ln1g, ln1b, xn, TOK);
  // 2. qkv = xn @ Wqkv
  gemm_kernel<1><<<dim3(18,129), dim3(256), 0, stream>>>(xn, Wqkv, nullptr, nullptr, qkvb, TOK, 1152, 384);
  // 2b. prompt qkv
  pqkv_kernel<<<dim3(18), dim3(256), 0, stream>>>(pe, Wqkv, pq);
  // 3. attention (MFMA flash + prompt cross-attn) -> ao
  attn_kernel<<<dim3(9,192), dim3(256), 0, stream>>>(qkvb, pq, gate, ao);
  // 4. xres = x + ao @ Wproj + bproj
  gemm_kernel<3><<<dim3(6,129), dim3(256), 0, stream>>>(ao, Wproj, bproj, x_in, xres, TOK, 384, 384);
  // 5. LN2
  ln_kernel<false><<<dim3((TOK*64)/256), dim3(256), 0, stream>>>((const void*)xres, ln2g, ln2b, xn, TOK);
  // 6. h1 = gelu(xn @ W1 + b1)
  gemm_kernel<2><<<dim3(24,129), dim3(256), 0, stream>>>(xn, W1, b1, nullptr, h1, TOK, 1536, 384);
  // 7. h = h1 @ W2 + b2
  gemm_kernel<0><<<dim3(6,129), dim3(256), 0, stream>>>(h1, W2, b2v, nullptr, hbuf, TOK, 384, 1536);
  // 8. adapter mid
  adapter_mid_kernel<<<dim3(TOK), dim3(256), 0, stream>>>(hbuf, adW, adb, adU, adub, adg, xres);
  // 9. fused local branch (MFMA) -> vis
  local_kernel<<<dim3(4096), dim3(512), 0, stream>>>(xres, idx, cidx, ln3g, ln3b, Bq, Bp, a1pb,
                                                     bng, bnb, bnm, bnv, ifmm, ccof, visb);
  // 10. interp
  interp_kernel<<<dim3(64,32), dim3(256), 0, stream>>>(c1, c2, visb, pcof, xres);
  // 11. final adapter -> d_out (dtype per flag)
  adapter_final_kernel<<<dim3(TOK), dim3(256), 0, stream>>>(xres, d1W, d1b, u1W, u1b, flag, d_out);
}

// Round 6
// 1109.063 us; speedup vs baseline: 6.4274x; 1.5337x over previous
//
#include <hip/hip_runtime.h>
#include <hip/hip_bf16.h>
#include <cstdint>
#include <cstddef>

// Problem constants: B=32, G=512, S=128, GS=32, P=10, C=384, H=6, D=64,
// HID=1536, RED=16, tokens per batch = 513.
typedef __hip_bfloat16 bf16;
constexpr int TOK = 32 * 513;   // 16416 rows in the residual stream

typedef __attribute__((ext_vector_type(8))) short short8;
typedef __attribute__((ext_vector_type(4))) float f32x4;

__device__ __forceinline__ float bflo(unsigned u){ return __uint_as_float(u << 16); }
__device__ __forceinline__ float bfhi(unsigned u){ return __uint_as_float(u & 0xffff0000u); }
__device__ __forceinline__ float b2f(bf16 x){ return __bfloat162float(x); }
__device__ __forceinline__ bf16  f2b(float x){ return __float2bfloat16(x); }
__device__ __forceinline__ float geluf(float x){ return 0.5f*x*(1.0f + erff(x*0.70710678118654752f)); }
__device__ __forceinline__ void unp8(uint4 u, float* f){
  f[0]=bflo(u.x); f[1]=bfhi(u.x); f[2]=bflo(u.y); f[3]=bfhi(u.y);
  f[4]=bflo(u.z); f[5]=bfhi(u.z); f[6]=bflo(u.w); f[7]=bfhi(u.w);
}
// Scalar decode robust to int32-vs-float32 materialization of Python scalars.
__device__ __forceinline__ float scal(const int* p){
  const int i = *p;
  if (i > -1000000 && i < 1000000) return (float)i;
  return __int_as_float(i);
}
__device__ __forceinline__ f32x4 mfma16(short8 a, short8 b, f32x4 c){
  return __builtin_amdgcn_mfma_f32_16x16x32_bf16(a, b, c, 0, 0, 0);
}

// ---------------------------------------------------------------------------
// Dtype detection: if any 16-bit half of x's first 2048 words, viewed as bf16,
// is NaN or |v|>1e6 => inputs are fp32 (flag=1). bf16 inputs (|x|<~6) => 0.
// ---------------------------------------------------------------------------
__global__ __launch_bounds__(256) void detect_kernel(const unsigned* __restrict__ x,
                                                     int* __restrict__ flag)
{
  const int t = threadIdx.x;
  bool bad = false;
  for (int i = t; i < 2048; i += 256){
    const unsigned u = x[i];
    const float a = fabsf(bflo(u)), b = fabsf(bfhi(u));
    if (!(a < 1e6f) || !(b < 1e6f)) bad = true;   // NaN fails the compare
  }
  __shared__ int s;
  if (t == 0) s = 0;
  __syncthreads();
  const unsigned long long m = __ballot(bad);
  if (m != 0ull && (t & 63) == 0) atomicOr(&s, 1);
  __syncthreads();
  if (t == 0) *flag = s;
}

// ---------------------------------------------------------------------------
// Canonicalize all float inputs to bf16 (copy if already bf16).
// ---------------------------------------------------------------------------
struct ConvArgs {
  const void* src[34];
  bf16*       dst[34];
  int         n[34];
};
__global__ __launch_bounds__(256) void convert_many(const int* __restrict__ flag, ConvArgs a)
{
  const int ii = blockIdx.y;
  const bool isf = (*flag != 0);
  const int n = a.n[ii];
  const void* s = a.src[ii];
  bf16* d = a.dst[ii];
  for (int i = blockIdx.x*256 + threadIdx.x; i < n; i += gridDim.x*256){
    d[i] = isf ? f2b(((const float*)s)[i]) : ((const bf16*)s)[i];
  }
}

// ---------------------------------------------------------------------------
// Shuffle weight W[K x N] (row-major) into MFMA B-fragment order:
// out[((n0*KT + k0)*64 + lane)*8 + j] = W[(k0*32 + (lane>>4)*8 + j)*N + n0*16 + (lane&15)]
// ---------------------------------------------------------------------------
__global__ __launch_bounds__(256) void shuffle_b(const bf16* __restrict__ W,
    bf16* __restrict__ out, int N, int KT, int NT)
{
  const int id = blockIdx.x*256 + threadIdx.x;
  if (id >= NT*KT*64) return;
  const int l  = id & 63;
  const int k0 = (id >> 6) % KT;
  const int n0 = (id >> 6) / KT;
  bf16 tmp[8];
  #pragma unroll
  for (int j = 0; j < 8; j++)
    tmp[j] = W[(size_t)(k0*32 + (l>>4)*8 + j)*N + n0*16 + (l&15)];
  *(uint4*)(out + (size_t)id*8) = *(const uint4*)tmp;
}

// ---------------------------------------------------------------------------
// LayerNorm: one wave per row of 384. Output bf16.
// ---------------------------------------------------------------------------
template<bool SRC_BF16>
__global__ __launch_bounds__(256) void ln_kernel(const void* __restrict__ src,
    const bf16* __restrict__ g, const bf16* __restrict__ b,
    bf16* __restrict__ out, int rows)
{
  const int wave = (blockIdx.x * blockDim.x + threadIdx.x) >> 6;
  const int lane = threadIdx.x & 63;
  if (wave >= rows) return;
  float v[6]; float s = 0.f, s2 = 0.f;
  #pragma unroll
  for (int i = 0; i < 6; i++){
    const int c = lane + 64*i;
    float x;
    if (SRC_BF16) x = b2f(((const bf16*)src)[(size_t)wave*384 + c]);
    else          x = ((const float*)src)[(size_t)wave*384 + c];
    v[i] = x; s += x; s2 += x*x;
  }
  #pragma unroll
  for (int mm = 32; mm; mm >>= 1){ s += __shfl_xor(s, mm); s2 += __shfl_xor(s2, mm); }
  const float mean = s * (1.f/384.f);
  const float rs = rsqrtf(s2 * (1.f/384.f) - mean*mean + 1e-5f);
  #pragma unroll
  for (int i = 0; i < 6; i++){
    const int c = lane + 64*i;
    out[(size_t)wave*384 + c] = f2b((v[i]-mean)*rs*b2f(g[c]) + b2f(b[c]));
  }
}

// ---------------------------------------------------------------------------
// MFMA GEMM: out[M,N] = A[M,K] @ W[K,N] (+bias, epilogue). A bf16 row-major,
// Bsh = W pre-shuffled into B-frag order. Block 128x64, BK=32, 256 thr.
// A staged in LDS fragment order (lane-contiguous b128 reads, conflict-free).
// EPI: 0 = bf16 out, +bias; 1 = bf16 out; 2 = bf16 out gelu(+bias);
//      3 = f32 out, +bias +bf16resid
// ---------------------------------------------------------------------------
template<int EPI>
__global__ __launch_bounds__(256) void mfma_gemm(
    const bf16* __restrict__ A, const bf16* __restrict__ Bsh,
    const bf16* __restrict__ bias, const bf16* __restrict__ resid,
    void* __restrict__ outv, int M, int N, int K)
{
  __shared__ __align__(16) bf16 sA[8*64*8];   // 8 m-frag-tiles of 128x32
  const int t = threadIdx.x, lane = t & 63, w = t >> 6;
  const int l15 = lane & 15, quad = lane >> 4;
  const int m0 = blockIdx.y * 128;
  const int n0t = blockIdx.x * 4;             // global n-tile base
  const int KT = K >> 5;
  f32x4 acc[2][4];
  #pragma unroll
  for (int i = 0; i < 2; i++){
    #pragma unroll
    for (int j = 0; j < 4; j++) acc[i][j] = f32x4{0.f,0.f,0.f,0.f};
  }
  const int arow = t >> 1, ac0 = (t & 1) * 16;
  const int amt = arow >> 4, al15 = arow & 15, aq0 = (ac0 >> 3);

  for (int ks = 0; ks < KT; ks++){
    uint4 u0 = {0,0,0,0}, u1 = {0,0,0,0};
    const int gm = m0 + arow;
    if (gm < M){
      const bf16* ap = A + (size_t)gm*K + ks*32 + ac0;
      u0 = *(const uint4*)ap; u1 = *(const uint4*)(ap + 8);
    }
    *(uint4*)(sA + ((amt*64 + aq0*16     + al15) << 3)) = u0;
    *(uint4*)(sA + ((amt*64 + (aq0+1)*16 + al15) << 3)) = u1;
    __syncthreads();
    short8 afr0 = *(const short8*)(sA + (((w*2+0)*64 + lane) << 3));
    short8 afr1 = *(const short8*)(sA + (((w*2+1)*64 + lane) << 3));
    #pragma unroll
    for (int nt = 0; nt < 4; nt++){
      const short8 b = *(const short8*)(Bsh + ((size_t)((n0t+nt)*KT + ks)*64 + lane)*8);
      acc[0][nt] = mfma16(afr0, b, acc[0][nt]);
      acc[1][nt] = mfma16(afr1, b, acc[1][nt]);
    }
    __syncthreads();
  }
  #pragma unroll
  for (int mt = 0; mt < 2; mt++){
    #pragma unroll
    for (int r = 0; r < 4; r++){
      const int gm = m0 + (w*2+mt)*16 + quad*4 + r;
      if (gm < M){
        #pragma unroll
        for (int nt = 0; nt < 4; nt++){
          const int gn = (n0t+nt)*16 + l15;
          float v = acc[mt][nt][r];
          const size_t o = (size_t)gm*N + gn;
          if (EPI == 0){ v += b2f(bias[gn]); ((bf16*)outv)[o] = f2b(v); }
          else if (EPI == 1){ ((bf16*)outv)[o] = f2b(v); }
          else if (EPI == 2){ v += b2f(bias[gn]); ((bf16*)outv)[o] = f2b(geluf(v)); }
          else { v += b2f(bias[gn]) + b2f(resid[o]); ((float*)outv)[o] = v; }
        }
      }
    }
  }
}

// ---------------------------------------------------------------------------
// Prompt QKV: (10 x 384) @ (384 x 1152) -> f32 (prompt used WITHOUT LN).
// ---------------------------------------------------------------------------
__global__ __launch_bounds__(256) void pqkv_kernel(const bf16* __restrict__ pe,
    const bf16* __restrict__ Wqkv, float* __restrict__ pq)
{
  const int n  = blockIdx.x*64 + (threadIdx.x & 63);
  const int rg = threadIdx.x >> 6;
  for (int r = rg; r < 10; r += 4){
    float s0 = 0.f, s1 = 0.f;
    for (int c = 0; c < 384; c += 2){
      s0 = fmaf(b2f(pe[(size_t)r*384+c]),   b2f(Wqkv[(size_t)c*1152 + n]),     s0);
      s1 = fmaf(b2f(pe[(size_t)r*384+c+1]), b2f(Wqkv[(size_t)(c+1)*1152 + n]), s1);
    }
    pq[(size_t)r*1152 + n] = s0 + s1;
  }
}

// ---------------------------------------------------------------------------
// Main attention (MFMA flash) + prompt cross-attention fused. (unchanged r5)
// ---------------------------------------------------------------------------
__global__ __launch_bounds__(256) void attn_kernel(
    const bf16* __restrict__ qkv, const float* __restrict__ pq,
    const bf16* __restrict__ gate, bf16* __restrict__ ao)
{
  __shared__ __align__(16) bf16 s_q[64*72];
  __shared__ __align__(16) bf16 s_k[64*72];
  __shared__ __align__(16) bf16 s_vT[64*72];
  __shared__ __align__(16) bf16 s_p[4*16*40];
  __shared__ __align__(16) bf16 s_pk[16*72];
  __shared__ __align__(16) bf16 s_pvT[64*40];
  const int bh = blockIdx.y;
  const int b = bh / 6, h = bh % 6;
  const int q0 = blockIdx.x * 64;
  const int t = threadIdx.x, lane = t & 63, w = t >> 6;
  const int l15 = lane & 15, quad = lane >> 4;

  {
    const int row = t >> 2, dc = (t & 3) * 16;
    const int tok = q0 + row;
    uint4 u0 = {0,0,0,0}, u1 = {0,0,0,0};
    if (tok < 513){
      const bf16* p = qkv + (size_t)(b*513 + tok)*1152 + h*64 + dc;
      u0 = *(const uint4*)p; u1 = *(const uint4*)(p + 8);
    }
    *(uint4*)(s_q + row*72 + dc)     = u0;
    *(uint4*)(s_q + row*72 + dc + 8) = u1;
  }
  {
    const int j = t >> 4, dc = (t & 15) * 4;
    float f[4] = {0.f,0.f,0.f,0.f};
    if (j < 10){
      const float* pk = pq + (size_t)j*1152 + 384 + h*64 + dc;
      f[0]=pk[0]; f[1]=pk[1]; f[2]=pk[2]; f[3]=pk[3];
    }
    bf16 tmp[4] = {f2b(f[0]),f2b(f[1]),f2b(f[2]),f2b(f[3])};
    *(uint2*)(s_pk + j*72 + dc) = *(const uint2*)tmp;
  }
  {
    const int d = t & 63, kg = t >> 6;
    #pragma unroll
    for (int kk = 0; kk < 8; kk++){
      const int key = kg*8 + kk;
      bf16 v = f2b(0.f);
      if (key < 10) v = f2b(pq[(size_t)key*1152 + 768 + h*64 + d]);
      s_pvT[d*40 + key] = v;
    }
  }

  float m_i[4], l_i[4];
  f32x4 oacc[4];
  #pragma unroll
  for (int r = 0; r < 4; r++){ m_i[r] = -30000.f; l_i[r] = 0.f; }
  #pragma unroll
  for (int nt = 0; nt < 4; nt++) oacc[nt] = f32x4{0.f,0.f,0.f,0.f};
  bf16* myp = s_p + w*16*40;
  const short8* aq = (const short8*)(s_q + (w*16 + l15)*72);

  for (int kt = 0; kt < 9; kt++){
    const int kb = kt*64;
    __syncthreads();
    {
      const int kp = t & 31, dg = t >> 5;
      const int key0 = kb + 2*kp;
      uint4 k0v = {0,0,0,0}, k1v = {0,0,0,0}, v0 = {0,0,0,0}, v1 = {0,0,0,0};
      if (key0 < 513){
        const bf16* base = qkv + (size_t)(b*513 + key0)*1152 + h*64 + dg*8;
        k0v = *(const uint4*)(base + 384);
        v0  = *(const uint4*)(base + 768);
      }
      if (key0 + 1 < 513){
        const bf16* base = qkv + (size_t)(b*513 + key0 + 1)*1152 + h*64 + dg*8;
        k1v = *(const uint4*)(base + 384);
        v1  = *(const uint4*)(base + 768);
      }
      *(uint4*)(s_k + (2*kp)*72   + dg*8) = k0v;
      *(uint4*)(s_k + (2*kp+1)*72 + dg*8) = k1v;
      const unsigned short* a0 = (const unsigned short*)&v0;
      const unsigned short* a1 = (const unsigned short*)&v1;
      unsigned* vt = (unsigned*)s_vT;
      #pragma unroll
      for (int j = 0; j < 8; j++)
        vt[(dg*8 + j)*36 + kp] = (unsigned)a0[j] | ((unsigned)a1[j] << 16);
    }
    __syncthreads();

    f32x4 sreg[4];
    #pragma unroll
    for (int nt = 0; nt < 4; nt++){
      f32x4 acc = f32x4{0.f,0.f,0.f,0.f};
      const short8* bk = (const short8*)(s_k + (nt*16 + l15)*72);
      acc = mfma16(aq[quad],     bk[quad],     acc);
      acc = mfma16(aq[4 + quad], bk[4 + quad], acc);
      const bool kvalid = (kb + nt*16 + l15) < 513;
      #pragma unroll
      for (int r = 0; r < 4; r++)
        sreg[nt][r] = kvalid ? acc[r]*0.125f : -30000.f;
    }
    float alpha[4];
    #pragma unroll
    for (int r = 0; r < 4; r++){
      float mx = fmaxf(fmaxf(sreg[0][r], sreg[1][r]), fmaxf(sreg[2][r], sreg[3][r]));
      #pragma unroll
      for (int mm = 8; mm; mm >>= 1) mx = fmaxf(mx, __shfl_xor(mx, mm));
      const float mn = fmaxf(m_i[r], mx);
      alpha[r] = __expf(m_i[r] - mn);
      m_i[r] = mn;
      float ps = 0.f;
      #pragma unroll
      for (int nt = 0; nt < 4; nt++){
        const float p = __expf(sreg[nt][r] - mn);
        sreg[nt][r] = p; ps += p;
      }
      #pragma unroll
      for (int mm = 8; mm; mm >>= 1) ps += __shfl_xor(ps, mm);
      l_i[r] = l_i[r]*alpha[r] + ps;
    }
    #pragma unroll
    for (int nt = 0; nt < 4; nt++){
      #pragma unroll
      for (int r = 0; r < 4; r++)
        myp[(quad*4 + r)*40 + nt*16 + l15] = f2b(sreg[nt][r]);
    }
    #pragma unroll
    for (int nt = 0; nt < 4; nt++){
      #pragma unroll
      for (int r = 0; r < 4; r++) oacc[nt][r] *= alpha[r];
    }
    const short8* ap = (const short8*)(myp + l15*40);
    #pragma unroll
    for (int nt = 0; nt < 4; nt++){
      const short8* bv = (const short8*)(s_vT + (nt*16 + l15)*72);
      oacc[nt] = mfma16(ap[quad],     bv[quad],     oacc[nt]);
      oacc[nt] = mfma16(ap[4 + quad], bv[4 + quad], oacc[nt]);
    }
  }

  f32x4 sp;
  {
    f32x4 acc = f32x4{0.f,0.f,0.f,0.f};
    const short8* bp = (const short8*)(s_pk + l15*72);
    acc = mfma16(aq[quad],     bp[quad],     acc);
    acc = mfma16(aq[4 + quad], bp[4 + quad], acc);
    #pragma unroll
    for (int r = 0; r < 4; r++)
      sp[r] = (l15 < 10) ? acc[r]*0.125f : -30000.f;
  }
  float psr[4];
  #pragma unroll
  for (int r = 0; r < 4; r++){
    float mx = sp[r];
    #pragma unroll
    for (int mm = 8; mm; mm >>= 1) mx = fmaxf(mx, __shfl_xor(mx, mm));
    const float p = __expf(sp[r] - mx);
    float ps = p;
    #pragma unroll
    for (int mm = 8; mm; mm >>= 1) ps += __shfl_xor(ps, mm);
    psr[r] = ps;
    myp[(quad*4 + r)*40 + l15]      = f2b(p);
    myp[(quad*4 + r)*40 + 16 + l15] = f2b(0.f);
  }
  f32x4 pva[4];
  {
    const short8* ap = (const short8*)(myp + l15*40);
    #pragma unroll
    for (int nt = 0; nt < 4; nt++){
      const short8* bv = (const short8*)(s_pvT + (nt*16 + l15)*40);
      pva[nt] = mfma16(ap[quad], bv[quad], f32x4{0.f,0.f,0.f,0.f});
    }
  }

  const float gh = b2f(gate[h]);
  #pragma unroll
  for (int r = 0; r < 4; r++){
    const int tok = q0 + w*16 + quad*4 + r;
    if (tok < 513){
      const float invl = 1.f/l_i[r];
      const float gps  = gh/psr[r];
      #pragma unroll
      for (int nt = 0; nt < 4; nt++){
        const float val = oacc[nt][r]*invl + pva[nt][r]*gps;
        ao[(size_t)(b*513 + tok)*384 + h*64 + nt*16 + l15] = f2b(val);
      }
    }
  }
}

// ---------------------------------------------------------------------------
// Adapter (mid): xres = ad_gate*(h + gelu(h@Wd+bd)@Wu + bu) + xres. 1 block/row.
// ---------------------------------------------------------------------------
__global__ __launch_bounds__(256) void adapter_mid_kernel(const bf16* __restrict__ h,
    const bf16* __restrict__ Wd, const bf16* __restrict__ bd,
    const bf16* __restrict__ Wu, const bf16* __restrict__ bu,
    const bf16* __restrict__ p_gate, float* __restrict__ xres)
{
  __shared__ float s_h[384];
  __shared__ float s_part[16][17];
  __shared__ float s_y[16];
  const size_t row = blockIdx.x;
  const int t = threadIdx.x;
  const bf16* hp = h + row*384;
  for (int c = t; c < 384; c += 256) s_h[c] = b2f(hp[c]);
  __syncthreads();
  const int o = t & 15, p = t >> 4;
  float part0 = 0.f, part1 = 0.f;
  for (int c = p; c < 384; c += 32){
    part0 = fmaf(s_h[c],    b2f(Wd[(size_t)c*16 + o]),      part0);
    part1 = fmaf(s_h[c+16], b2f(Wd[(size_t)(c+16)*16 + o]), part1);
  }
  s_part[o][p] = part0 + part1;
  __syncthreads();
  if (t < 16){
    float sum = 0.f;
    #pragma unroll
    for (int pp = 0; pp < 16; pp++) sum += s_part[t][pp];
    s_y[t] = geluf(sum + b2f(bd[t]));
  }
  __syncthreads();
  const float g = b2f(p_gate[0]);
  for (int c = t; c < 384; c += 256){
    float up = 0.f;
    #pragma unroll
    for (int o2 = 0; o2 < 16; o2++) up = fmaf(s_y[o2], b2f(Wu[(size_t)o2*384 + c]), up);
    const float had = s_h[c] + up + b2f(bu[c]);
    xres[row*384 + c] = g*had + xres[row*384 + c];
  }
}

// ---------------------------------------------------------------------------
// Final adapter: out = xres + gelu(xres@Wd+bd)@Wu + bu. Output dtype per flag.
// ---------------------------------------------------------------------------
__global__ __launch_bounds__(256) void adapter_final_kernel(const float* __restrict__ xr,
    const bf16* __restrict__ Wd, const bf16* __restrict__ bd,
    const bf16* __restrict__ Wu, const bf16* __restrict__ bu,
    const int* __restrict__ flag, void* __restrict__ out)
{
  __shared__ float s_h[384];
  __shared__ float s_part[16][17];
  __shared__ float s_y[16];
  const size_t row = blockIdx.x;
  const int t = threadIdx.x;
  const float* hp = xr + row*384;
  for (int c = t; c < 384; c += 256) s_h[c] = hp[c];
  __syncthreads();
  const int o = t & 15, p = t >> 4;
  float part0 = 0.f, part1 = 0.f;
  for (int c = p; c < 384; c += 32){
    part0 = fmaf(s_h[c],    b2f(Wd[(size_t)c*16 + o]),      part0);
    part1 = fmaf(s_h[c+16], b2f(Wd[(size_t)(c+16)*16 + o]), part1);
  }
  s_part[o][p] = part0 + part1;
  __syncthreads();
  if (t < 16){
    float sum = 0.f;
    #pragma unroll
    for (int pp = 0; pp < 16; pp++) sum += s_part[t][pp];
    s_y[t] = geluf(sum + b2f(bd[t]));
  }
  __syncthreads();
  const bool isf = (*flag != 0);
  for (int c = t; c < 384; c += 256){
    float up = 0.f;
    #pragma unroll
    for (int o2 = 0; o2 < 16; o2++) up = fmaf(s_y[o2], b2f(Wu[(size_t)o2*384 + c]), up);
    const float v = s_h[c] + up + b2f(bu[c]);
    if (isf) ((float*)out)[row*384 + c] = v;
    else     ((bf16*)out)[row*384 + c] = f2b(v);
  }
}

// ---------------------------------------------------------------------------
// Fused local branch (MFMA, fragment-order LDS): one block (512 thr) per group.
// All MFMA operand loads are lane-contiguous ds_read_b128 (conflict-free).
// Frag layouts: A-frag[m=l15][k=quad*8+j], B-frag[k=quad*8+j][n=l15],
// C/D[row=quad*4+r][col=l15]; frag buffer addr = (tile*64 + lane)*8 + j.
// ---------------------------------------------------------------------------
__global__ __launch_bounds__(512) void local_kernel(
    const float* __restrict__ xres, const int* __restrict__ idx, const int* __restrict__ cidx,
    const bf16* __restrict__ ln3g, const bf16* __restrict__ ln3b,
    const bf16* __restrict__ Bq, const bf16* __restrict__ Bp, const bf16* __restrict__ bp1,
    const bf16* __restrict__ bng, const bf16* __restrict__ bnb,
    const bf16* __restrict__ bnm, const bf16* __restrict__ bnv,
    const int* __restrict__ p_ifmm, const int* __restrict__ p_ccof,
    float* __restrict__ vis)
{
  __shared__ __align__(16) bf16 sX[2*12*64*8];  // X A-frags (2 mt x 12 k0)
  __shared__ __align__(16) bf16 sQf[4*64*8];    // Q A-frags (2mt x 2k0); O after PV
  __shared__ __align__(16) bf16 sKf[4*64*8];    // K B-frags (2nt x 2k0)
  __shared__ __align__(16) bf16 sVf[4*64*8];    // V B-frags (4 nt)
  __shared__ __align__(16) bf16 sPf[2*64*8];    // P A-frags (2 mt)
  __shared__ int s_tok[32];

  const int g = blockIdx.x;
  const int t = threadIdx.x, lane = t & 63, w = t >> 6;
  const int l15 = lane & 15, quad = lane >> 4;

  if (t < 32){
    const int r = idx[g*32 + t];
    s_tok[t] = (r >> 9)*513 + 1 + (r & 511);
  }
  __syncthreads();

  // LN3 -> sX in A-frag order
  #pragma unroll
  for (int i = 0; i < 4; i++){
    const int r = w*4 + i;
    const int mt = r >> 4, l15r = r & 15;
    const float* xp = xres + (size_t)s_tok[r]*384;
    float vv[6]; float s = 0.f, s2 = 0.f;
    #pragma unroll
    for (int c6 = 0; c6 < 6; c6++){ float x = xp[lane + 64*c6]; vv[c6] = x; s += x; s2 += x*x; }
    #pragma unroll
    for (int mm = 32; mm; mm >>= 1){ s += __shfl_xor(s, mm); s2 += __shfl_xor(s2, mm); }
    const float mean = s*(1.f/384.f);
    const float rs = rsqrtf(s2*(1.f/384.f) - mean*mean + 1e-5f);
    #pragma unroll
    for (int c6 = 0; c6 < 6; c6++){
      const int c = lane + 64*c6;
      const int k0 = c >> 5, qd = (c >> 3) & 3, j = c & 7;
      sX[((mt*12 + k0)*64 + qd*16 + l15r)*8 + j] =
        f2b((vv[c6]-mean)*rs*b2f(ln3g[c]) + b2f(ln3b[c]));
    }
  }
  __syncthreads();

  f32x4 accp[3][2];
  #pragma unroll
  for (int a = 0; a < 3; a++){
    #pragma unroll
    for (int m = 0; m < 2; m++) accp[a][m] = f32x4{0.f,0.f,0.f,0.f};
  }

  for (int h = 0; h < 6; h++){
    // ---- QKV: 24 tiles (2 mt x 12 jj); wave w takes {w, w+8, w+16}
    #pragma unroll
    for (int tt = 0; tt < 3; tt++){
      const int id = w + tt*8;
      const int mt = id / 12, jj = id % 12;
      const int grp = jj >> 2, jc = jj & 3;        // 0=Q,1=K,2=V
      const int gnt = grp*24 + h*4 + jc;
      f32x4 acc = f32x4{0.f,0.f,0.f,0.f};
      #pragma unroll 4
      for (int k0 = 0; k0 < 12; k0++){
        const short8 a = *(const short8*)(sX + ((mt*12 + k0)*64 + lane)*8);
        const short8 b = *(const short8*)(Bq + ((size_t)(gnt*12 + k0)*64 + lane)*8);
        acc = mfma16(a, b, acc);
      }
      if (grp < 2){ // Q/K: value X→[tok=mt*16+quad*4+r][d=jc*16+l15] into frag order
        const int dloc = jc*16 + l15;
        const int k0w = dloc >> 5, qdw = (dloc >> 3) & 3, jw = dloc & 7;
        bf16* dst = (grp == 0) ? sQf : sKf;
        #pragma unroll
        for (int r = 0; r < 4; r++)
          dst[((mt*2 + k0w)*64 + qdw*16 + quad*4 + r)*8 + jw] = f2b(acc[r]);
      } else {      // V: B-frag [key][d]: nt=jc
        #pragma unroll
        for (int r = 0; r < 4; r++){
          const int key = mt*16 + quad*4 + r;
          sVf[(jc*64 + (key >> 3)*16 + l15)*8 + (key & 7)] = f2b(acc[r]);
        }
      }
    }
    __syncthreads();

    // ---- S = QK^T*scale + softmax (waves 0,1; mt=w), P -> sPf (A-frag)
    if (w < 2){
      const int mt = w;
      f32x4 sr[2];
      #pragma unroll
      for (int nt = 0; nt < 2; nt++){
        f32x4 acc = f32x4{0.f,0.f,0.f,0.f};
        #pragma unroll
        for (int k0 = 0; k0 < 2; k0++){
          const short8 a = *(const short8*)(sQf + ((mt*2 + k0)*64 + lane)*8);
          const short8 b = *(const short8*)(sKf + ((nt*2 + k0)*64 + lane)*8);
          acc = mfma16(a, b, acc);
        }
        #pragma unroll
        for (int r = 0; r < 4; r++) sr[nt][r] = acc[r]*0.125f;
      }
      #pragma unroll
      for (int r = 0; r < 4; r++){
        float mx = fmaxf(sr[0][r], sr[1][r]);
        #pragma unroll
        for (int mm = 8; mm; mm >>= 1) mx = fmaxf(mx, __shfl_xor(mx, mm));
        const float e0 = __expf(sr[0][r] - mx), e1 = __expf(sr[1][r] - mx);
        float sm = e0 + e1;
        #pragma unroll
        for (int mm = 8; mm; mm >>= 1) sm += __shfl_xor(sm, mm);
        const float inv = 1.f/sm;
        const int m = quad*4 + r;
        // col0 = l15, col1 = 16+l15
        sPf[(mt*64 + (l15 >> 3)*16       + m)*8 + (l15 & 7)] = f2b(e0*inv);
        sPf[(mt*64 + (2 + (l15 >> 3))*16 + m)*8 + (l15 & 7)] = f2b(e1*inv);
      }
    }
    __syncthreads();

    // ---- O = P V (8 tiles: mt=w&1, nt=w>>1); O -> sQf (A-frag, Q dead)
    {
      const int mt = w & 1, nt = w >> 1;
      const short8 a = *(const short8*)(sPf + (mt*64 + lane)*8);
      const short8 b = *(const short8*)(sVf + (nt*64 + lane)*8);
      const f32x4 o = mfma16(a, b, f32x4{0.f,0.f,0.f,0.f});
      const int k0w = nt >> 1, qdw = (nt & 1)*2 + (l15 >> 3), jw = l15 & 7;
      #pragma unroll
      for (int r = 0; r < 4; r++)
        sQf[((mt*2 + k0w)*64 + qdw*16 + quad*4 + r)*8 + jw] = f2b(o[r]);
    }
    __syncthreads();

    // ---- proj partial: accp += O_h @ Wp[h*64:(h+1)*64, :]
    {
      short8 afr[2][2];
      #pragma unroll
      for (int mt = 0; mt < 2; mt++){
        #pragma unroll
        for (int k0l = 0; k0l < 2; k0l++)
          afr[mt][k0l] = *(const short8*)(sQf + ((mt*2 + k0l)*64 + lane)*8);
      }
      #pragma unroll
      for (int tt = 0; tt < 3; tt++){
        const int nt = w*3 + tt;
        #pragma unroll
        for (int k0l = 0; k0l < 2; k0l++){
          const short8 b = *(const short8*)(Bp + ((size_t)(nt*12 + 2*h + k0l)*64 + lane)*8);
          accp[tt][0] = mfma16(afr[0][k0l], b, accp[tt][0]);
          accp[tt][1] = mfma16(afr[1][k0l], b, accp[tt][1]);
        }
      }
    }
    __syncthreads();   // protect sQf/sKf/sVf before next head
  }

  // ---- epilogue: +bias +resid, pool, BN, gelu, +ccof*center
  const float fmm  = scal(p_ifmm);
  const float ccof = scal(p_ccof);
  const int cr = cidx[g];
  const int ctok = (cr >> 9)*513 + 1 + (cr & 511);
  #pragma unroll
  for (int tt = 0; tt < 3; tt++){
    const int n = (w*3 + tt)*16 + l15;
    const float bb = b2f(bp1[n]);
    float mx = -3e30f, sm = 0.f;
    #pragma unroll
    for (int mt = 0; mt < 2; mt++){
      #pragma unroll
      for (int r = 0; r < 4; r++){
        const int tok = mt*16 + quad*4 + r;
        const float v = accp[tt][mt][r] + bb + xres[(size_t)s_tok[tok]*384 + n];
        mx = fmaxf(mx, v); sm += v;
      }
    }
    mx = fmaxf(mx, __shfl_xor(mx, 16)); sm += __shfl_xor(sm, 16);
    mx = fmaxf(mx, __shfl_xor(mx, 32)); sm += __shfl_xor(sm, 32);
    if (quad == 0){
      const float lc = (fmm != 0.f) ? (mx + sm*(1.f/32.f)) : mx;
      const float nr = (lc - b2f(bnm[n])) * rsqrtf(b2f(bnv[n]) + 1e-5f) * b2f(bng[n]) + b2f(bnb[n]);
      vis[(size_t)g*384 + n] = geluf(nr) + ccof * xres[(size_t)ctok*384 + n];
    }
  }
}

// ---------------------------------------------------------------------------
// Inverse-distance interpolation: xt[b,n,:] += pro_cof * sum_s w[n,s] vis[b,s,:].
// ---------------------------------------------------------------------------
__global__ __launch_bounds__(256) void interp_kernel(const bf16* __restrict__ c1,
    const bf16* __restrict__ c2, const float* __restrict__ vis,
    const int* __restrict__ p_pcof, float* __restrict__ xres)
{
  __shared__ float s_w[8][128];
  __shared__ float s_red[2];
  const int b = blockIdx.y;
  const int n0 = blockIdx.x * 8;
  const int t = threadIdx.x;
  for (int ni = 0; ni < 8; ni++){
    const int n = n0 + ni;
    float wv = 0.f;
    if (t < 128){
      float d2 = 0.f;
      #pragma unroll
      for (int k = 0; k < 3; k++){
        const float a = b2f(c1[((size_t)b*512 + n)*3 + k]);
        const float c = b2f(c2[((size_t)b*128 + t)*3 + k]);
        const float df = a - c; d2 += df*df;
      }
      wv = 1.f/(d2 + 1e-8f);
    }
    float rsum = wv;
    #pragma unroll
    for (int mm = 32; mm; mm >>= 1) rsum += __shfl_xor(rsum, mm);
    if (((t & 63) == 0) && t < 128) s_red[t >> 6] = rsum;
    __syncthreads();
    const float tot = s_red[0] + s_red[1];
    if (t < 128) s_w[ni][t] = wv / tot;
    __syncthreads();
  }
  float acc1[8], acc2[8];
  #pragma unroll
  for (int ni = 0; ni < 8; ni++){ acc1[ni] = 0.f; acc2[ni] = 0.f; }
  for (int s = 0; s < 128; s++){
    const float* vp = vis + ((size_t)b*128 + s)*384;
    const float v1 = vp[t];
    const float v2 = (t < 128) ? vp[t + 256] : 0.f;
    #pragma unroll
    for (int ni = 0; ni < 8; ni++){
      const float wn = s_w[ni][s];
      acc1[ni] = fmaf(wn, v1, acc1[ni]);
      acc2[ni] = fmaf(wn, v2, acc2[ni]);
    }
  }
  const float pc = scal(p_pcof);
  #pragma unroll
  for (int ni = 0; ni < 8; ni++){
    const int tok = b*513 + 1 + n0 + ni;
    xres[(size_t)tok*384 + t] += pc*acc1[ni];
    if (t < 128) xres[(size_t)tok*384 + t + 256] += pc*acc2[ni];
  }
}

// ---------------------------------------------------------------------------
extern "C" void kernel_launch(void* const* d_in, const int* in_sizes, int n_in,
                              void* d_out, int out_size, void* d_ws, size_t ws_size,
                              hipStream_t stream)
{
  (void)n_in; (void)out_size; (void)ws_size;
  const int*  idx   = (const int*)d_in[35];
  const int*  cidx  = (const int*)d_in[36];
  const int*  ifmm  = (const int*)d_in[38];
  const int*  pcof  = (const int*)d_in[39];
  const int*  ccof  = (const int*)d_in[40];

  size_t off = 0;
  auto alloc = [&](size_t bytes) -> void* {
    void* p = (char*)d_ws + off; off += (bytes + 255) & ~(size_t)255; return p;
  };
  int*   flag = (int*)  alloc(sizeof(int));
  float* xres = (float*)alloc((size_t)TOK*384*4);
  bf16*  slab = (bf16*) alloc((size_t)TOK*1536*2);
  bf16*  xn   = (bf16*) alloc((size_t)TOK*384*2);
  float* pq   = (float*)alloc((size_t)10*1152*4);
  bf16*  Bq   = (bf16*) alloc((size_t)72*12*64*8*2);   // shuffled a1_Wqkv
  bf16*  Bp   = (bf16*) alloc((size_t)24*12*64*8*2);   // shuffled a1_Wproj
  bf16*  Bqkv = (bf16*) alloc((size_t)72*12*64*8*2);   // shuffled Wqkv
  bf16*  Bw1  = (bf16*) alloc((size_t)96*12*64*8*2);   // shuffled W1
  bf16*  Bw2  = (bf16*) alloc((size_t)24*48*64*8*2);   // shuffled W2
  bf16*  Bwp  = (bf16*) alloc((size_t)24*12*64*8*2);   // shuffled Wproj

  bf16*  qkvb = slab;
  bf16*  x_c  = slab + (size_t)TOK*1152;
  bf16*  h1   = slab;
  float* visb = (float*)slab;
  bf16*  ao   = xn;
  bf16*  hbuf = xn;

  const int conv_ids[34] = {0,1,2,4,5,6,7,8,9,10,11,12,13,14,15,16,17,
                            18,19,20,21,22,23,24,25,26,27,28,29,30,31,32,33,34};
  ConvArgs ca;
  bf16* canon[41];
  int maxn = 1;
  for (int k = 0; k < 34; k++){
    const int i = conv_ids[k];
    const int n = in_sizes[i];
    bf16* dst = (i == 0) ? x_c : (bf16*)alloc((size_t)n*2);
    ca.src[k] = d_in[i]; ca.dst[k] = dst; ca.n[k] = n;
    canon[i] = dst;
    if (n > maxn) maxn = n;
  }
  detect_kernel<<<dim3(1), dim3(256), 0, stream>>>((const unsigned*)d_in[0], flag);
  {
    int gx = (maxn + 256*64 - 1) / (256*64); if (gx > 64) gx = 64; if (gx < 1) gx = 1;
    convert_many<<<dim3(gx, 34), dim3(256), 0, stream>>>(flag, ca);
  }

  const bf16 *x_in = canon[0], *c1 = canon[1], *c2 = canon[2], *pe = canon[4],
             *ln1g = canon[5], *ln1b = canon[6], *Wqkv = canon[7], *Wproj = canon[8],
             *bproj = canon[9], *gate = canon[10], *ln2g = canon[11], *ln2b = canon[12],
             *W1 = canon[13], *b1 = canon[14], *W2 = canon[15], *b2v = canon[16],
             *adW = canon[17], *adb = canon[18], *adU = canon[19], *adub = canon[20],
             *adg = canon[21], *bng = canon[22], *bnb = canon[23], *bnm = canon[24],
             *bnv = canon[25], *ln3g = canon[26], *ln3b = canon[27], *a1W = canon[28],
             *a1P = canon[29], *a1pb = canon[30], *d1W = canon[31], *d1b = canon[32],
             *u1W = canon[33], *u1b = canon[34];

  // weight shuffles (once per launch, ~3.5 MB total)
  shuffle_b<<<dim3(216), dim3(256), 0, stream>>>(a1W, Bq, 1152, 12, 72);
  shuffle_b<<<dim3(72),  dim3(256), 0, stream>>>(a1P, Bp, 384, 12, 24);
  shuffle_b<<<dim3(216), dim3(256), 0, stream>>>(Wqkv, Bqkv, 1152, 12, 72);
  shuffle_b<<<dim3(288), dim3(256), 0, stream>>>(W1, Bw1, 1536, 12, 96);
  shuffle_b<<<dim3(288), dim3(256), 0, stream>>>(W2, Bw2, 384, 48, 24);
  shuffle_b<<<dim3(72),  dim3(256), 0, stream>>>(Wproj, Bwp, 384, 12, 24);

  // 1. LN1
  ln_kernel<true><<<dim3((TOK*64)/256), dim3(256), 0, stream>>>((const void*)x_in, ln1g, ln1b, xn, TOK);
  // 2. qkv = xn @ Wqkv (MFMA)
  mfma_gemm<1><<<dim3(18,129), dim3(256), 0, stream>>>(xn, Bqkv, nullptr, nullptr, qkvb, TOK, 1152, 384);
  // 2b. prompt qkv
  pqkv_kernel<<<dim3(18), dim3(256), 0, stream>>>(pe, Wqkv, pq);
  // 3. attention (MFMA flash + prompt cross-attn) -> ao
  attn_kernel<<<dim3(9,192), dim3(256), 0, stream>>>(qkvb, pq, gate, ao);
  // 4. xres = x + ao @ Wproj + bproj (MFMA)
  mfma_gemm<3><<<dim3(6,129), dim3(256), 0, stream>>>(ao, Bwp, bproj, x_in, xres, TOK, 384, 384);
  // 5. LN2
  ln_kernel<false><<<dim3((TOK*64)/256), dim3(256), 0, stream>>>((const void*)xres, ln2g, ln2b, xn, TOK);
  // 6. h1 = gelu(xn @ W1 + b1) (MFMA)
  mfma_gemm<2><<<dim3(24,129), dim3(256), 0, stream>>>(xn, Bw1, b1, nullptr, h1, TOK, 1536, 384);
  // 7. h = h1 @ W2 + b2 (MFMA)
  mfma_gemm<0><<<dim3(6,129), dim3(256), 0, stream>>>(h1, Bw2, b2v, nullptr, hbuf, TOK, 384, 1536);
  // 8. adapter mid
  adapter_mid_kernel<<<dim3(TOK), dim3(256), 0, stream>>>(hbuf, adW, adb, adU, adub, adg, xres);
  // 9. fused local branch (MFMA, frag-order LDS) -> vis
  local_kernel<<<dim3(4096), dim3(512), 0, stream>>>(xres, idx, cidx, ln3g, ln3b, Bq, Bp, a1pb,
                                                     bng, bnb, bnm, bnv, ifmm, ccof, visb);
  // 10. interp
  interp_kernel<<<dim3(64,32), dim3(256), 0, stream>>>(c1, c2, visb, pcof, xres);
  // 11. final adapter -> d_out (dtype per flag)
  adapter_final_kernel<<<dim3(TOK), dim3(256), 0, stream>>>(xres, d1W, d1b, u1W, u1b, flag, d_out);
}

// Round 7
// 1003.911 us; speedup vs baseline: 7.1006x; 1.1047x over previous
//
#include <hip/hip_runtime.h>
#include <hip/hip_bf16.h>
#include <cstdint>
#include <cstddef>

// Problem constants: B=32, G=512, S=128, GS=32, P=10, C=384, H=6, D=64,
// HID=1536, RED=16, tokens per batch = 513.
typedef __hip_bfloat16 bf16;
constexpr int TOK = 32 * 513;   // 16416 rows in the residual stream

typedef __attribute__((ext_vector_type(8))) short short8;
typedef __attribute__((ext_vector_type(4))) float f32x4;

__device__ __forceinline__ float bflo(unsigned u){ return __uint_as_float(u << 16); }
__device__ __forceinline__ float bfhi(unsigned u){ return __uint_as_float(u & 0xffff0000u); }
__device__ __forceinline__ float b2f(bf16 x){ return __bfloat162float(x); }
__device__ __forceinline__ bf16  f2b(float x){ return __float2bfloat16(x); }
__device__ __forceinline__ float geluf(float x){ return 0.5f*x*(1.0f + erff(x*0.70710678118654752f)); }
__device__ __forceinline__ void unp8(uint4 u, float* f){
  f[0]=bflo(u.x); f[1]=bfhi(u.x); f[2]=bflo(u.y); f[3]=bfhi(u.y);
  f[4]=bflo(u.z); f[5]=bfhi(u.z); f[6]=bflo(u.w); f[7]=bfhi(u.w);
}
// Scalar decode robust to int32-vs-float32 materialization of Python scalars.
__device__ __forceinline__ float scal(const int* p){
  const int i = *p;
  if (i > -1000000 && i < 1000000) return (float)i;
  return __int_as_float(i);
}
__device__ __forceinline__ f32x4 mfma16(short8 a, short8 b, f32x4 c){
  return __builtin_amdgcn_mfma_f32_16x16x32_bf16(a, b, c, 0, 0, 0);
}

// ---------------------------------------------------------------------------
// Dtype detection: fp32 vs bf16 inputs.
// ---------------------------------------------------------------------------
__global__ __launch_bounds__(256) void detect_kernel(const unsigned* __restrict__ x,
                                                     int* __restrict__ flag)
{
  const int t = threadIdx.x;
  bool bad = false;
  for (int i = t; i < 2048; i += 256){
    const unsigned u = x[i];
    const float a = fabsf(bflo(u)), b = fabsf(bfhi(u));
    if (!(a < 1e6f) || !(b < 1e6f)) bad = true;
  }
  __shared__ int s;
  if (t == 0) s = 0;
  __syncthreads();
  const unsigned long long m = __ballot(bad);
  if (m != 0ull && (t & 63) == 0) atomicOr(&s, 1);
  __syncthreads();
  if (t == 0) *flag = s;
}

// ---------------------------------------------------------------------------
// Canonicalize all float inputs to bf16 (copy if already bf16).
// ---------------------------------------------------------------------------
struct ConvArgs {
  const void* src[34];
  bf16*       dst[34];
  int         n[34];
};
__global__ __launch_bounds__(256) void convert_many(const int* __restrict__ flag, ConvArgs a)
{
  const int ii = blockIdx.y;
  const bool isf = (*flag != 0);
  const int n = a.n[ii];
  const void* s = a.src[ii];
  bf16* d = a.dst[ii];
  for (int i = blockIdx.x*256 + threadIdx.x; i < n; i += gridDim.x*256){
    d[i] = isf ? f2b(((const float*)s)[i]) : ((const bf16*)s)[i];
  }
}

// ---------------------------------------------------------------------------
// Shuffle weight W[K x N] (row-major) into MFMA B-fragment order.
// ---------------------------------------------------------------------------
__global__ __launch_bounds__(256) void shuffle_b(const bf16* __restrict__ W,
    bf16* __restrict__ out, int N, int KT, int NT)
{
  const int id = blockIdx.x*256 + threadIdx.x;
  if (id >= NT*KT*64) return;
  const int l  = id & 63;
  const int k0 = (id >> 6) % KT;
  const int n0 = (id >> 6) / KT;
  bf16 tmp[8];
  #pragma unroll
  for (int j = 0; j < 8; j++)
    tmp[j] = W[(size_t)(k0*32 + (l>>4)*8 + j)*N + n0*16 + (l&15)];
  *(uint4*)(out + (size_t)id*8) = *(const uint4*)tmp;
}

// ---------------------------------------------------------------------------
// LayerNorm: one wave per row of 384. Output bf16.
// ---------------------------------------------------------------------------
template<bool SRC_BF16>
__global__ __launch_bounds__(256) void ln_kernel(const void* __restrict__ src,
    const bf16* __restrict__ g, const bf16* __restrict__ b,
    bf16* __restrict__ out, int rows)
{
  const int wave = (blockIdx.x * blockDim.x + threadIdx.x) >> 6;
  const int lane = threadIdx.x & 63;
  if (wave >= rows) return;
  float v[6]; float s = 0.f, s2 = 0.f;
  #pragma unroll
  for (int i = 0; i < 6; i++){
    const int c = lane + 64*i;
    float x;
    if (SRC_BF16) x = b2f(((const bf16*)src)[(size_t)wave*384 + c]);
    else          x = ((const float*)src)[(size_t)wave*384 + c];
    v[i] = x; s += x; s2 += x*x;
  }
  #pragma unroll
  for (int mm = 32; mm; mm >>= 1){ s += __shfl_xor(s, mm); s2 += __shfl_xor(s2, mm); }
  const float mean = s * (1.f/384.f);
  const float rs = rsqrtf(s2 * (1.f/384.f) - mean*mean + 1e-5f);
  #pragma unroll
  for (int i = 0; i < 6; i++){
    const int c = lane + 64*i;
    out[(size_t)wave*384 + c] = f2b((v[i]-mean)*rs*b2f(g[c]) + b2f(b[c]));
  }
}

// ---------------------------------------------------------------------------
// LN3 over the 16384 non-cls tokens: row r -> xres token (r>>9)*513+1+(r&511).
// ---------------------------------------------------------------------------
__global__ __launch_bounds__(256) void ln3_kernel(const float* __restrict__ xres,
    const bf16* __restrict__ g, const bf16* __restrict__ b, bf16* __restrict__ out)
{
  const int r = (blockIdx.x * blockDim.x + threadIdx.x) >> 6;
  const int lane = threadIdx.x & 63;
  if (r >= 16384) return;
  const int tok = (r >> 9)*513 + 1 + (r & 511);
  const float* xp = xres + (size_t)tok*384;
  float v[6]; float s = 0.f, s2 = 0.f;
  #pragma unroll
  for (int i = 0; i < 6; i++){
    const float x = xp[lane + 64*i];
    v[i] = x; s += x; s2 += x*x;
  }
  #pragma unroll
  for (int mm = 32; mm; mm >>= 1){ s += __shfl_xor(s, mm); s2 += __shfl_xor(s2, mm); }
  const float mean = s * (1.f/384.f);
  const float rs = rsqrtf(s2 * (1.f/384.f) - mean*mean + 1e-5f);
  #pragma unroll
  for (int i = 0; i < 6; i++){
    const int c = lane + 64*i;
    out[(size_t)r*384 + c] = f2b((v[i]-mean)*rs*b2f(g[c]) + b2f(b[c]));
  }
}

// ---------------------------------------------------------------------------
// MFMA GEMM: out[M,N] = A[M,K] @ W[K,N] (+bias, epilogue). A bf16 row-major,
// Bsh = W pre-shuffled to B-frag order. Block 128x128, BK=32, 256 thr (2x2
// wave grid, 4x4 16x16 tiles per wave). A staged in LDS fragment order.
// EPI: 0 = bf16 out, +bias; 1 = bf16 out; 2 = bf16 out gelu(+bias);
//      3 = f32 out, +bias +bf16resid
// ---------------------------------------------------------------------------
template<int EPI>
__global__ __launch_bounds__(256) void mfma_gemm(
    const bf16* __restrict__ A, const bf16* __restrict__ Bsh,
    const bf16* __restrict__ bias, const bf16* __restrict__ resid,
    void* __restrict__ outv, int M, int N, int K)
{
  __shared__ __align__(16) bf16 sA[8*64*8];   // 128x32 A tile in frag order
  const int t = threadIdx.x, lane = t & 63, w = t >> 6;
  const int l15 = lane & 15, quad = lane >> 4;
  const int wm = w & 1, wn = w >> 1;          // 2x2 wave grid
  const int m0 = blockIdx.y * 128;
  const int n0t = blockIdx.x * 8 + wn * 4;    // this wave's global n-tile base
  const int KT = K >> 5;
  f32x4 acc[4][4];
  #pragma unroll
  for (int i = 0; i < 4; i++){
    #pragma unroll
    for (int j = 0; j < 4; j++) acc[i][j] = f32x4{0.f,0.f,0.f,0.f};
  }
  const int arow = t >> 1, ac0 = (t & 1) * 16;
  const int amt = arow >> 4, al15 = arow & 15, aq0 = (ac0 >> 3);

  for (int ks = 0; ks < KT; ks++){
    uint4 u0 = {0,0,0,0}, u1 = {0,0,0,0};
    const int gm = m0 + arow;
    if (gm < M){
      const bf16* ap = A + (size_t)gm*K + ks*32 + ac0;
      u0 = *(const uint4*)ap; u1 = *(const uint4*)(ap + 8);
    }
    *(uint4*)(sA + ((amt*64 + aq0*16     + al15) << 3)) = u0;
    *(uint4*)(sA + ((amt*64 + (aq0+1)*16 + al15) << 3)) = u1;
    __syncthreads();
    short8 afr[4];
    #pragma unroll
    for (int i = 0; i < 4; i++)
      afr[i] = *(const short8*)(sA + (((wm*4+i)*64 + lane) << 3));
    #pragma unroll
    for (int j = 0; j < 4; j++){
      const short8 b = *(const short8*)(Bsh + ((size_t)((n0t+j)*KT + ks)*64 + lane)*8);
      #pragma unroll
      for (int i = 0; i < 4; i++) acc[i][j] = mfma16(afr[i], b, acc[i][j]);
    }
    __syncthreads();
  }
  #pragma unroll
  for (int i = 0; i < 4; i++){
    #pragma unroll
    for (int r = 0; r < 4; r++){
      const int gm = m0 + (wm*4+i)*16 + quad*4 + r;
      if (gm < M){
        #pragma unroll
        for (int j = 0; j < 4; j++){
          const int gn = (n0t+j)*16 + l15;
          float v = acc[i][j][r];
          const size_t o = (size_t)gm*N + gn;
          if (EPI == 0){ v += b2f(bias[gn]); ((bf16*)outv)[o] = f2b(v); }
          else if (EPI == 1){ ((bf16*)outv)[o] = f2b(v); }
          else if (EPI == 2){ v += b2f(bias[gn]); ((bf16*)outv)[o] = f2b(geluf(v)); }
          else { v += b2f(bias[gn]) + b2f(resid[o]); ((float*)outv)[o] = v; }
        }
      }
    }
  }
}

// ---------------------------------------------------------------------------
// Prompt QKV: (10 x 384) @ (384 x 1152) -> f32 (prompt used WITHOUT LN).
// ---------------------------------------------------------------------------
__global__ __launch_bounds__(256) void pqkv_kernel(const bf16* __restrict__ pe,
    const bf16* __restrict__ Wqkv, float* __restrict__ pq)
{
  const int n  = blockIdx.x*64 + (threadIdx.x & 63);
  const int rg = threadIdx.x >> 6;
  for (int r = rg; r < 10; r += 4){
    float s0 = 0.f, s1 = 0.f;
    for (int c = 0; c < 384; c += 2){
      s0 = fmaf(b2f(pe[(size_t)r*384+c]),   b2f(Wqkv[(size_t)c*1152 + n]),     s0);
      s1 = fmaf(b2f(pe[(size_t)r*384+c+1]), b2f(Wqkv[(size_t)(c+1)*1152 + n]), s1);
    }
    pq[(size_t)r*1152 + n] = s0 + s1;
  }
}

// ---------------------------------------------------------------------------
// Main attention (MFMA flash) + prompt cross-attention fused. (unchanged r5)
// ---------------------------------------------------------------------------
__global__ __launch_bounds__(256) void attn_kernel(
    const bf16* __restrict__ qkv, const float* __restrict__ pq,
    const bf16* __restrict__ gate, bf16* __restrict__ ao)
{
  __shared__ __align__(16) bf16 s_q[64*72];
  __shared__ __align__(16) bf16 s_k[64*72];
  __shared__ __align__(16) bf16 s_vT[64*72];
  __shared__ __align__(16) bf16 s_p[4*16*40];
  __shared__ __align__(16) bf16 s_pk[16*72];
  __shared__ __align__(16) bf16 s_pvT[64*40];
  const int bh = blockIdx.y;
  const int b = bh / 6, h = bh % 6;
  const int q0 = blockIdx.x * 64;
  const int t = threadIdx.x, lane = t & 63, w = t >> 6;
  const int l15 = lane & 15, quad = lane >> 4;

  {
    const int row = t >> 2, dc = (t & 3) * 16;
    const int tok = q0 + row;
    uint4 u0 = {0,0,0,0}, u1 = {0,0,0,0};
    if (tok < 513){
      const bf16* p = qkv + (size_t)(b*513 + tok)*1152 + h*64 + dc;
      u0 = *(const uint4*)p; u1 = *(const uint4*)(p + 8);
    }
    *(uint4*)(s_q + row*72 + dc)     = u0;
    *(uint4*)(s_q + row*72 + dc + 8) = u1;
  }
  {
    const int j = t >> 4, dc = (t & 15) * 4;
    float f[4] = {0.f,0.f,0.f,0.f};
    if (j < 10){
      const float* pk = pq + (size_t)j*1152 + 384 + h*64 + dc;
      f[0]=pk[0]; f[1]=pk[1]; f[2]=pk[2]; f[3]=pk[3];
    }
    bf16 tmp[4] = {f2b(f[0]),f2b(f[1]),f2b(f[2]),f2b(f[3])};
    *(uint2*)(s_pk + j*72 + dc) = *(const uint2*)tmp;
  }
  {
    const int d = t & 63, kg = t >> 6;
    #pragma unroll
    for (int kk = 0; kk < 8; kk++){
      const int key = kg*8 + kk;
      bf16 v = f2b(0.f);
      if (key < 10) v = f2b(pq[(size_t)key*1152 + 768 + h*64 + d]);
      s_pvT[d*40 + key] = v;
    }
  }

  float m_i[4], l_i[4];
  f32x4 oacc[4];
  #pragma unroll
  for (int r = 0; r < 4; r++){ m_i[r] = -30000.f; l_i[r] = 0.f; }
  #pragma unroll
  for (int nt = 0; nt < 4; nt++) oacc[nt] = f32x4{0.f,0.f,0.f,0.f};
  bf16* myp = s_p + w*16*40;
  const short8* aq = (const short8*)(s_q + (w*16 + l15)*72);

  for (int kt = 0; kt < 9; kt++){
    const int kb = kt*64;
    __syncthreads();
    {
      const int kp = t & 31, dg = t >> 5;
      const int key0 = kb + 2*kp;
      uint4 k0v = {0,0,0,0}, k1v = {0,0,0,0}, v0 = {0,0,0,0}, v1 = {0,0,0,0};
      if (key0 < 513){
        const bf16* base = qkv + (size_t)(b*513 + key0)*1152 + h*64 + dg*8;
        k0v = *(const uint4*)(base + 384);
        v0  = *(const uint4*)(base + 768);
      }
      if (key0 + 1 < 513){
        const bf16* base = qkv + (size_t)(b*513 + key0 + 1)*1152 + h*64 + dg*8;
        k1v = *(const uint4*)(base + 384);
        v1  = *(const uint4*)(base + 768);
      }
      *(uint4*)(s_k + (2*kp)*72   + dg*8) = k0v;
      *(uint4*)(s_k + (2*kp+1)*72 + dg*8) = k1v;
      const unsigned short* a0 = (const unsigned short*)&v0;
      const unsigned short* a1 = (const unsigned short*)&v1;
      unsigned* vt = (unsigned*)s_vT;
      #pragma unroll
      for (int j = 0; j < 8; j++)
        vt[(dg*8 + j)*36 + kp] = (unsigned)a0[j] | ((unsigned)a1[j] << 16);
    }
    __syncthreads();

    f32x4 sreg[4];
    #pragma unroll
    for (int nt = 0; nt < 4; nt++){
      f32x4 acc = f32x4{0.f,0.f,0.f,0.f};
      const short8* bk = (const short8*)(s_k + (nt*16 + l15)*72);
      acc = mfma16(aq[quad],     bk[quad],     acc);
      acc = mfma16(aq[4 + quad], bk[4 + quad], acc);
      const bool kvalid = (kb + nt*16 + l15) < 513;
      #pragma unroll
      for (int r = 0; r < 4; r++)
        sreg[nt][r] = kvalid ? acc[r]*0.125f : -30000.f;
    }
    float alpha[4];
    #pragma unroll
    for (int r = 0; r < 4; r++){
      float mx = fmaxf(fmaxf(sreg[0][r], sreg[1][r]), fmaxf(sreg[2][r], sreg[3][r]));
      #pragma unroll
      for (int mm = 8; mm; mm >>= 1) mx = fmaxf(mx, __shfl_xor(mx, mm));
      const float mn = fmaxf(m_i[r], mx);
      alpha[r] = __expf(m_i[r] - mn);
      m_i[r] = mn;
      float ps = 0.f;
      #pragma unroll
      for (int nt = 0; nt < 4; nt++){
        const float p = __expf(sreg[nt][r] - mn);
        sreg[nt][r] = p; ps += p;
      }
      #pragma unroll
      for (int mm = 8; mm; mm >>= 1) ps += __shfl_xor(ps, mm);
      l_i[r] = l_i[r]*alpha[r] + ps;
    }
    #pragma unroll
    for (int nt = 0; nt < 4; nt++){
      #pragma unroll
      for (int r = 0; r < 4; r++)
        myp[(quad*4 + r)*40 + nt*16 + l15] = f2b(sreg[nt][r]);
    }
    #pragma unroll
    for (int nt = 0; nt < 4; nt++){
      #pragma unroll
      for (int r = 0; r < 4; r++) oacc[nt][r] *= alpha[r];
    }
    const short8* ap = (const short8*)(myp + l15*40);
    #pragma unroll
    for (int nt = 0; nt < 4; nt++){
      const short8* bv = (const short8*)(s_vT + (nt*16 + l15)*72);
      oacc[nt] = mfma16(ap[quad],     bv[quad],     oacc[nt]);
      oacc[nt] = mfma16(ap[4 + quad], bv[4 + quad], oacc[nt]);
    }
  }

  f32x4 sp;
  {
    f32x4 acc = f32x4{0.f,0.f,0.f,0.f};
    const short8* bp = (const short8*)(s_pk + l15*72);
    acc = mfma16(aq[quad],     bp[quad],     acc);
    acc = mfma16(aq[4 + quad], bp[4 + quad], acc);
    #pragma unroll
    for (int r = 0; r < 4; r++)
      sp[r] = (l15 < 10) ? acc[r]*0.125f : -30000.f;
  }
  float psr[4];
  #pragma unroll
  for (int r = 0; r < 4; r++){
    float mx = sp[r];
    #pragma unroll
    for (int mm = 8; mm; mm >>= 1) mx = fmaxf(mx, __shfl_xor(mx, mm));
    const float p = __expf(sp[r] - mx);
    float ps = p;
    #pragma unroll
    for (int mm = 8; mm; mm >>= 1) ps += __shfl_xor(ps, mm);
    psr[r] = ps;
    myp[(quad*4 + r)*40 + l15]      = f2b(p);
    myp[(quad*4 + r)*40 + 16 + l15] = f2b(0.f);
  }
  f32x4 pva[4];
  {
    const short8* ap = (const short8*)(myp + l15*40);
    #pragma unroll
    for (int nt = 0; nt < 4; nt++){
      const short8* bv = (const short8*)(s_pvT + (nt*16 + l15)*40);
      pva[nt] = mfma16(ap[quad], bv[quad], f32x4{0.f,0.f,0.f,0.f});
    }
  }

  const float gh = b2f(gate[h]);
  #pragma unroll
  for (int r = 0; r < 4; r++){
    const int tok = q0 + w*16 + quad*4 + r;
    if (tok < 513){
      const float invl = 1.f/l_i[r];
      const float gps  = gh/psr[r];
      #pragma unroll
      for (int nt = 0; nt < 4; nt++){
        const float val = oacc[nt][r]*invl + pva[nt][r]*gps;
        ao[(size_t)(b*513 + tok)*384 + h*64 + nt*16 + l15] = f2b(val);
      }
    }
  }
}

// ---------------------------------------------------------------------------
// Adapter (mid): xres = ad_gate*(h + gelu(h@Wd+bd)@Wu + bu) + xres. 1 block/row.
// ---------------------------------------------------------------------------
__global__ __launch_bounds__(256) void adapter_mid_kernel(const bf16* __restrict__ h,
    const bf16* __restrict__ Wd, const bf16* __restrict__ bd,
    const bf16* __restrict__ Wu, const bf16* __restrict__ bu,
    const bf16* __restrict__ p_gate, float* __restrict__ xres)
{
  __shared__ float s_h[384];
  __shared__ float s_part[16][17];
  __shared__ float s_y[16];
  const size_t row = blockIdx.x;
  const int t = threadIdx.x;
  const bf16* hp = h + row*384;
  for (int c = t; c < 384; c += 256) s_h[c] = b2f(hp[c]);
  __syncthreads();
  const int o = t & 15, p = t >> 4;
  float part0 = 0.f, part1 = 0.f;
  for (int c = p; c < 384; c += 32){
    part0 = fmaf(s_h[c],    b2f(Wd[(size_t)c*16 + o]),      part0);
    part1 = fmaf(s_h[c+16], b2f(Wd[(size_t)(c+16)*16 + o]), part1);
  }
  s_part[o][p] = part0 + part1;
  __syncthreads();
  if (t < 16){
    float sum = 0.f;
    #pragma unroll
    for (int pp = 0; pp < 16; pp++) sum += s_part[t][pp];
    s_y[t] = geluf(sum + b2f(bd[t]));
  }
  __syncthreads();
  const float g = b2f(p_gate[0]);
  for (int c = t; c < 384; c += 256){
    float up = 0.f;
    #pragma unroll
    for (int o2 = 0; o2 < 16; o2++) up = fmaf(s_y[o2], b2f(Wu[(size_t)o2*384 + c]), up);
    const float had = s_h[c] + up + b2f(bu[c]);
    xres[row*384 + c] = g*had + xres[row*384 + c];
  }
}

// ---------------------------------------------------------------------------
// Final adapter: out = xres + gelu(xres@Wd+bd)@Wu + bu. Output dtype per flag.
// ---------------------------------------------------------------------------
__global__ __launch_bounds__(256) void adapter_final_kernel(const float* __restrict__ xr,
    const bf16* __restrict__ Wd, const bf16* __restrict__ bd,
    const bf16* __restrict__ Wu, const bf16* __restrict__ bu,
    const int* __restrict__ flag, void* __restrict__ out)
{
  __shared__ float s_h[384];
  __shared__ float s_part[16][17];
  __shared__ float s_y[16];
  const size_t row = blockIdx.x;
  const int t = threadIdx.x;
  const float* hp = xr + row*384;
  for (int c = t; c < 384; c += 256) s_h[c] = hp[c];
  __syncthreads();
  const int o = t & 15, p = t >> 4;
  float part0 = 0.f, part1 = 0.f;
  for (int c = p; c < 384; c += 32){
    part0 = fmaf(s_h[c],    b2f(Wd[(size_t)c*16 + o]),      part0);
    part1 = fmaf(s_h[c+16], b2f(Wd[(size_t)(c+16)*16 + o]), part1);
  }
  s_part[o][p] = part0 + part1;
  __syncthreads();
  if (t < 16){
    float sum = 0.f;
    #pragma unroll
    for (int pp = 0; pp < 16; pp++) sum += s_part[t][pp];
    s_y[t] = geluf(sum + b2f(bd[t]));
  }
  __syncthreads();
  const bool isf = (*flag != 0);
  for (int c = t; c < 384; c += 256){
    float up = 0.f;
    #pragma unroll
    for (int o2 = 0; o2 < 16; o2++) up = fmaf(s_y[o2], b2f(Wu[(size_t)o2*384 + c]), up);
    const float v = s_h[c] + up + b2f(bu[c]);
    if (isf) ((float*)out)[row*384 + c] = v;
    else     ((bf16*)out)[row*384 + c] = f2b(v);
  }
}

// ---------------------------------------------------------------------------
// Fused local branch v2: QKV is precomputed per-token (qkv3, deduped 8x).
// One block (512 thr, 8 waves) per group: gather 32 rows of qkv3 into
// per-head MFMA frag-order LDS, then per head: S -> softmax -> PV -> proj,
// then pool/BN/GELU epilogue. All MFMA operand reads are lane-contiguous b128.
// ---------------------------------------------------------------------------
__global__ __launch_bounds__(512) void local_kernel(
    const bf16* __restrict__ qkv3, const float* __restrict__ xres,
    const int* __restrict__ idx, const int* __restrict__ cidx,
    const bf16* __restrict__ Bp, const bf16* __restrict__ bp1,
    const bf16* __restrict__ bng, const bf16* __restrict__ bnb,
    const bf16* __restrict__ bnm, const bf16* __restrict__ bnv,
    const int* __restrict__ p_ifmm, const int* __restrict__ p_ccof,
    float* __restrict__ vis)
{
  __shared__ __align__(16) bf16 sQ[6*4*64*8];  // Q A-frags [h][mt*2+k0][lane][8]
  __shared__ __align__(16) bf16 sK[6*4*64*8];  // K B-frags [h][nt*2+k0][lane][8]
  __shared__ __align__(16) bf16 sV[6*4*64*8];  // V B-frags [h][nt][lane][8]
  __shared__ __align__(16) bf16 sP[2*64*8];    // P A-frags per mt
  __shared__ __align__(16) bf16 sO[4*64*8];    // O A-frags [mt*2+k0]
  __shared__ int s_flat[32];
  __shared__ int s_tok[32];

  const int g = blockIdx.x;
  const int t = threadIdx.x, lane = t & 63, w = t >> 6;
  const int l15 = lane & 15, quad = lane >> 4;

  if (t < 32){
    const int r = idx[g*32 + t];
    s_flat[t] = r;
    s_tok[t]  = (r >> 9)*513 + 1 + (r & 511);
  }
  __syncthreads();

  // gather: 32 rows x 144 16B-chunks -> frag-order LDS
  for (int ch = t; ch < 4608; ch += 512){
    const int row = ch / 144;
    const int c0  = (ch % 144) * 8;
    const uint4 u = *(const uint4*)(qkv3 + (size_t)s_flat[row]*1152 + c0);
    const int grp = c0 / 384;
    const int rem = c0 - grp*384;
    const int h = rem >> 6, d0 = rem & 63;
    if (grp < 2){
      const int addr = ((h*4 + (row>>4)*2 + (d0>>5))*64 + ((d0>>3)&3)*16 + (row&15))*8;
      if (grp == 0) *(uint4*)(sQ + addr) = u;
      else          *(uint4*)(sK + addr) = u;
    } else {
      const bf16* sv = (const bf16*)&u;
      #pragma unroll
      for (int j2 = 0; j2 < 8; j2++){
        const int d = d0 + j2;
        sV[((h*4 + (d>>4))*64 + (row>>3)*16 + (d&15))*8 + (row&7)] = sv[j2];
      }
    }
  }
  __syncthreads();

  f32x4 accp[3][2];
  #pragma unroll
  for (int a = 0; a < 3; a++){
    #pragma unroll
    for (int m = 0; m < 2; m++) accp[a][m] = f32x4{0.f,0.f,0.f,0.f};
  }

  for (int h = 0; h < 6; h++){
    // ---- S = QK^T*scale + softmax (waves 0,1; mt=w), P -> sP (A-frag)
    if (w < 2){
      const int mt = w;
      f32x4 sr[2];
      #pragma unroll
      for (int nt = 0; nt < 2; nt++){
        f32x4 acc = f32x4{0.f,0.f,0.f,0.f};
        #pragma unroll
        for (int k0 = 0; k0 < 2; k0++){
          const short8 a = *(const short8*)(sQ + ((h*4 + mt*2 + k0)*64 + lane)*8);
          const short8 b = *(const short8*)(sK + ((h*4 + nt*2 + k0)*64 + lane)*8);
          acc = mfma16(a, b, acc);
        }
        #pragma unroll
        for (int r = 0; r < 4; r++) sr[nt][r] = acc[r]*0.125f;
      }
      #pragma unroll
      for (int r = 0; r < 4; r++){
        float mx = fmaxf(sr[0][r], sr[1][r]);
        #pragma unroll
        for (int mm = 8; mm; mm >>= 1) mx = fmaxf(mx, __shfl_xor(mx, mm));
        const float e0 = __expf(sr[0][r] - mx), e1 = __expf(sr[1][r] - mx);
        float sm = e0 + e1;
        #pragma unroll
        for (int mm = 8; mm; mm >>= 1) sm += __shfl_xor(sm, mm);
        const float inv = 1.f/sm;
        const int m = quad*4 + r;
        sP[(mt*64 + (l15 >> 3)*16       + m)*8 + (l15 & 7)] = f2b(e0*inv);
        sP[(mt*64 + (2 + (l15 >> 3))*16 + m)*8 + (l15 & 7)] = f2b(e1*inv);
      }
    }
    __syncthreads();

    // ---- O = P V (8 tiles: mt=w&1, nt=w>>1); O -> sO (A-frag)
    {
      const int mt = w & 1, nt = w >> 1;
      const short8 a = *(const short8*)(sP + (mt*64 + lane)*8);
      const short8 b = *(const short8*)(sV + ((h*4 + nt)*64 + lane)*8);
      const f32x4 o = mfma16(a, b, f32x4{0.f,0.f,0.f,0.f});
      const int k0w = nt >> 1, qdw = (nt & 1)*2 + (l15 >> 3), jw = l15 & 7;
      #pragma unroll
      for (int r = 0; r < 4; r++)
        sO[((mt*2 + k0w)*64 + qdw*16 + quad*4 + r)*8 + jw] = f2b(o[r]);
    }
    __syncthreads();

    // ---- proj partial: accp += O_h @ Wp[h*64:(h+1)*64, :]
    {
      short8 afr[2][2];
      #pragma unroll
      for (int mt = 0; mt < 2; mt++){
        #pragma unroll
        for (int k0l = 0; k0l < 2; k0l++)
          afr[mt][k0l] = *(const short8*)(sO + ((mt*2 + k0l)*64 + lane)*8);
      }
      #pragma unroll
      for (int tt = 0; tt < 3; tt++){
        const int nt = w*3 + tt;
        #pragma unroll
        for (int k0l = 0; k0l < 2; k0l++){
          const short8 b = *(const short8*)(Bp + ((size_t)(nt*12 + 2*h + k0l)*64 + lane)*8);
          accp[tt][0] = mfma16(afr[0][k0l], b, accp[tt][0]);
          accp[tt][1] = mfma16(afr[1][k0l], b, accp[tt][1]);
        }
      }
    }
    __syncthreads();   // protect sP/sO before next head
  }

  // ---- epilogue: +bias +resid, pool, BN, gelu, +ccof*center
  const float fmm  = scal(p_ifmm);
  const float ccof = scal(p_ccof);
  const int cr = cidx[g];
  const int ctok = (cr >> 9)*513 + 1 + (cr & 511);
  #pragma unroll
  for (int tt = 0; tt < 3; tt++){
    const int n = (w*3 + tt)*16 + l15;
    const float bb = b2f(bp1[n]);
    float mx = -3e30f, sm = 0.f;
    #pragma unroll
    for (int mt = 0; mt < 2; mt++){
      #pragma unroll
      for (int r = 0; r < 4; r++){
        const int tok = mt*16 + quad*4 + r;
        const float v = accp[tt][mt][r] + bb + xres[(size_t)s_tok[tok]*384 + n];
        mx = fmaxf(mx, v); sm += v;
      }
    }
    mx = fmaxf(mx, __shfl_xor(mx, 16)); sm += __shfl_xor(sm, 16);
    mx = fmaxf(mx, __shfl_xor(mx, 32)); sm += __shfl_xor(sm, 32);
    if (quad == 0){
      const float lc = (fmm != 0.f) ? (mx + sm*(1.f/32.f)) : mx;
      const float nr = (lc - b2f(bnm[n])) * rsqrtf(b2f(bnv[n]) + 1e-5f) * b2f(bng[n]) + b2f(bnb[n]);
      vis[(size_t)g*384 + n] = geluf(nr) + ccof * xres[(size_t)ctok*384 + n];
    }
  }
}

// ---------------------------------------------------------------------------
// Inverse-distance interpolation: xt[b,n,:] += pro_cof * sum_s w[n,s] vis[b,s,:].
// ---------------------------------------------------------------------------
__global__ __launch_bounds__(256) void interp_kernel(const bf16* __restrict__ c1,
    const bf16* __restrict__ c2, const float* __restrict__ vis,
    const int* __restrict__ p_pcof, float* __restrict__ xres)
{
  __shared__ float s_w[8][128];
  __shared__ float s_red[2];
  const int b = blockIdx.y;
  const int n0 = blockIdx.x * 8;
  const int t = threadIdx.x;
  for (int ni = 0; ni < 8; ni++){
    const int n = n0 + ni;
    float wv = 0.f;
    if (t < 128){
      float d2 = 0.f;
      #pragma unroll
      for (int k = 0; k < 3; k++){
        const float a = b2f(c1[((size_t)b*512 + n)*3 + k]);
        const float c = b2f(c2[((size_t)b*128 + t)*3 + k]);
        const float df = a - c; d2 += df*df;
      }
      wv = 1.f/(d2 + 1e-8f);
    }
    float rsum = wv;
    #pragma unroll
    for (int mm = 32; mm; mm >>= 1) rsum += __shfl_xor(rsum, mm);
    if (((t & 63) == 0) && t < 128) s_red[t >> 6] = rsum;
    __syncthreads();
    const float tot = s_red[0] + s_red[1];
    if (t < 128) s_w[ni][t] = wv / tot;
    __syncthreads();
  }
  float acc1[8], acc2[8];
  #pragma unroll
  for (int ni = 0; ni < 8; ni++){ acc1[ni] = 0.f; acc2[ni] = 0.f; }
  for (int s = 0; s < 128; s++){
    const float* vp = vis + ((size_t)b*128 + s)*384;
    const float v1 = vp[t];
    const float v2 = (t < 128) ? vp[t + 256] : 0.f;
    #pragma unroll
    for (int ni = 0; ni < 8; ni++){
      const float wn = s_w[ni][s];
      acc1[ni] = fmaf(wn, v1, acc1[ni]);
      acc2[ni] = fmaf(wn, v2, acc2[ni]);
    }
  }
  const float pc = scal(p_pcof);
  #pragma unroll
  for (int ni = 0; ni < 8; ni++){
    const int tok = b*513 + 1 + n0 + ni;
    xres[(size_t)tok*384 + t] += pc*acc1[ni];
    if (t < 128) xres[(size_t)tok*384 + t + 256] += pc*acc2[ni];
  }
}

// ---------------------------------------------------------------------------
extern "C" void kernel_launch(void* const* d_in, const int* in_sizes, int n_in,
                              void* d_out, int out_size, void* d_ws, size_t ws_size,
                              hipStream_t stream)
{
  (void)n_in; (void)out_size; (void)ws_size;
  const int*  idx   = (const int*)d_in[35];
  const int*  cidx  = (const int*)d_in[36];
  const int*  ifmm  = (const int*)d_in[38];
  const int*  pcof  = (const int*)d_in[39];
  const int*  ccof  = (const int*)d_in[40];

  size_t off = 0;
  auto alloc = [&](size_t bytes) -> void* {
    void* p = (char*)d_ws + off; off += (bytes + 255) & ~(size_t)255; return p;
  };
  int*   flag = (int*)  alloc(sizeof(int));
  float* xres = (float*)alloc((size_t)TOK*384*4);
  bf16*  slab = (bf16*) alloc((size_t)TOK*1536*2);
  bf16*  xn   = (bf16*) alloc((size_t)TOK*384*2);
  float* pq   = (float*)alloc((size_t)10*1152*4);
  bf16*  Bq   = (bf16*) alloc((size_t)72*12*64*8*2);   // shuffled a1_Wqkv
  bf16*  Bp   = (bf16*) alloc((size_t)24*12*64*8*2);   // shuffled a1_Wproj
  bf16*  Bqkv = (bf16*) alloc((size_t)72*12*64*8*2);   // shuffled Wqkv
  bf16*  Bw1  = (bf16*) alloc((size_t)96*12*64*8*2);   // shuffled W1
  bf16*  Bw2  = (bf16*) alloc((size_t)24*48*64*8*2);   // shuffled W2
  bf16*  Bwp  = (bf16*) alloc((size_t)24*12*64*8*2);   // shuffled Wproj

  // slab overlays (time-phased):
  //   A: qkvb [0, TOK*1152) + canonical-x [TOK*1152, TOK*1536)
  //   B: h1   [0, TOK*1536)
  //   C: qkv3 [0, 16384*1152) + xln3 [TOK*1152, +16384*384)
  bf16*  qkvb = slab;
  bf16*  x_c  = slab + (size_t)TOK*1152;
  bf16*  h1   = slab;
  bf16*  qkv3 = slab;
  bf16*  xln3 = slab + (size_t)TOK*1152;
  bf16*  ao   = xn;
  bf16*  hbuf = xn;
  float* visb = (float*)xn;   // vis (6.3 MB) overlays xn after h is consumed

  const int conv_ids[34] = {0,1,2,4,5,6,7,8,9,10,11,12,13,14,15,16,17,
                            18,19,20,21,22,23,24,25,26,27,28,29,30,31,32,33,34};
  ConvArgs ca;
  bf16* canon[41];
  int maxn = 1;
  for (int k = 0; k < 34; k++){
    const int i = conv_ids[k];
    const int n = in_sizes[i];
    bf16* dst = (i == 0) ? x_c : (bf16*)alloc((size_t)n*2);
    ca.src[k] = d_in[i]; ca.dst[k] = dst; ca.n[k] = n;
    canon[i] = dst;
    if (n > maxn) maxn = n;
  }
  detect_kernel<<<dim3(1), dim3(256), 0, stream>>>((const unsigned*)d_in[0], flag);
  {
    int gx = (maxn + 256*64 - 1) / (256*64); if (gx > 64) gx = 64; if (gx < 1) gx = 1;
    convert_many<<<dim3(gx, 34), dim3(256), 0, stream>>>(flag, ca);
  }

  const bf16 *x_in = canon[0], *c1 = canon[1], *c2 = canon[2], *pe = canon[4],
             *ln1g = canon[5], *ln1b = canon[6], *Wqkv = canon[7], *Wproj = canon[8],
             *bproj = canon[9], *gate = canon[10], *ln2g = canon[11], *ln2b = canon[12],
             *W1 = canon[13], *b1 = canon[14], *W2 = canon[15], *b2v = canon[16],
             *adW = canon[17], *adb = canon[18], *adU = canon[19], *adub = canon[20],
             *adg = canon[21], *bng = canon[22], *bnb = canon[23], *bnm = canon[24],
             *bnv = canon[25], *ln3g = canon[26], *ln3b = canon[27], *a1W = canon[28],
             *a1P = canon[29], *a1pb = canon[30], *d1W = canon[31], *d1b = canon[32],
             *u1W = canon[33], *u1b = canon[34];

  // weight shuffles (once per launch)
  shuffle_b<<<dim3(216), dim3(256), 0, stream>>>(a1W, Bq, 1152, 12, 72);
  shuffle_b<<<dim3(72),  dim3(256), 0, stream>>>(a1P, Bp, 384, 12, 24);
  shuffle_b<<<dim3(216), dim3(256), 0, stream>>>(Wqkv, Bqkv, 1152, 12, 72);
  shuffle_b<<<dim3(288), dim3(256), 0, stream>>>(W1, Bw1, 1536, 12, 96);
  shuffle_b<<<dim3(288), dim3(256), 0, stream>>>(W2, Bw2, 384, 48, 24);
  shuffle_b<<<dim3(72),  dim3(256), 0, stream>>>(Wproj, Bwp, 384, 12, 24);

  // 1. LN1
  ln_kernel<true><<<dim3((TOK*64)/256), dim3(256), 0, stream>>>((const void*)x_in, ln1g, ln1b, xn, TOK);
  // 2. qkv = xn @ Wqkv (MFMA 128x128)
  mfma_gemm<1><<<dim3(9,129), dim3(256), 0, stream>>>(xn, Bqkv, nullptr, nullptr, qkvb, TOK, 1152, 384);
  // 2b. prompt qkv
  pqkv_kernel<<<dim3(18), dim3(256), 0, stream>>>(pe, Wqkv, pq);
  // 3. attention (MFMA flash + prompt cross-attn) -> ao
  attn_kernel<<<dim3(9,192), dim3(256), 0, stream>>>(qkvb, pq, gate, ao);
  // 4. xres = x + ao @ Wproj + bproj
  mfma_gemm<3><<<dim3(3,129), dim3(256), 0, stream>>>(ao, Bwp, bproj, x_in, xres, TOK, 384, 384);
  // 5. LN2
  ln_kernel<false><<<dim3((TOK*64)/256), dim3(256), 0, stream>>>((const void*)xres, ln2g, ln2b, xn, TOK);
  // 6. h1 = gelu(xn @ W1 + b1)
  mfma_gemm<2><<<dim3(12,129), dim3(256), 0, stream>>>(xn, Bw1, b1, nullptr, h1, TOK, 1536, 384);
  // 7. h = h1 @ W2 + b2
  mfma_gemm<0><<<dim3(3,129), dim3(256), 0, stream>>>(h1, Bw2, b2v, nullptr, hbuf, TOK, 384, 1536);
  // 8. adapter mid
  adapter_mid_kernel<<<dim3(TOK), dim3(256), 0, stream>>>(hbuf, adW, adb, adU, adub, adg, xres);
  // 8b. LN3 per token (deduped) -> xln3
  ln3_kernel<<<dim3((16384*64)/256), dim3(256), 0, stream>>>(xres, ln3g, ln3b, xln3);
  // 8c. qkv3 = xln3 @ a1_Wqkv (deduped, flat MFMA GEMM)
  mfma_gemm<1><<<dim3(9,128), dim3(256), 0, stream>>>(xln3, Bq, nullptr, nullptr, qkv3, 16384, 1152, 384);
  // 9. local branch v2 (gather + attn + proj + pool) -> vis
  local_kernel<<<dim3(4096), dim3(512), 0, stream>>>(qkv3, xres, idx, cidx, Bp, a1pb,
                                                     bng, bnb, bnm, bnv, ifmm, ccof, visb);
  // 10. interp
  interp_kernel<<<dim3(64,32), dim3(256), 0, stream>>>(c1, c2, visb, pcof, xres);
  // 11. final adapter -> d_out (dtype per flag)
  adapter_final_kernel<<<dim3(TOK), dim3(256), 0, stream>>>(xres, d1W, d1b, u1W, u1b, flag, d_out);
}